// Round 7
// baseline (348.126 us; speedup 1.0000x reference)
//
#include <hip/hip_runtime.h>
#include <math.h>

namespace {

constexpr int kN   = 1024;
constexpr int kDim = 768;
constexpr int kH   = 12;
constexpr int kBH  = 48;
constexpr float kScale = 0.125f;  // HD^-0.5 (folded into q at k_qkv)

typedef __attribute__((ext_vector_type(8))) short short8;
typedef __attribute__((ext_vector_type(4))) short short4v;
typedef __attribute__((ext_vector_type(4))) float f32x4;
typedef __attribute__((ext_vector_type(16))) float f32x16;
typedef __attribute__((ext_vector_type(4))) uint uint4v;

#define MFMA(a, b, c)   __builtin_amdgcn_mfma_f32_16x16x32_bf16(a, b, c, 0, 0, 0)
#define MFMA32(a, b, c) __builtin_amdgcn_mfma_f32_32x32x16_bf16(a, b, c, 0, 0, 0)

// ---------- bf16 helpers (round-to-nearest-even) ----------
__device__ __forceinline__ ushort f2bf(float f) {
  uint u = __builtin_bit_cast(uint, f);
  u += 0x7fffu + ((u >> 16) & 1u);
  return (ushort)(u >> 16);
}
__device__ __forceinline__ float bf2f(ushort h) {
  uint u = ((uint)h) << 16;
  return __builtin_bit_cast(float, u);
}
__device__ __forceinline__ void split8(const float* f, short8& hi, short8& lo) {
  #pragma unroll
  for (int i = 0; i < 8; i++) {
    const ushort h = f2bf(f[i]);
    hi[i] = (short)h;
    lo[i] = (short)f2bf(f[i] - bf2f(h));
  }
}
__device__ __forceinline__ uint packbf(float a, float b) {
  return (uint)f2bf(a) | ((uint)f2bf(b) << 16);
}

// ---------- async global->LDS, 16B per lane ----------
__device__ __forceinline__ void gl16(const short* g, short* l) {
  __builtin_amdgcn_global_load_lds(
      (const __attribute__((address_space(1))) void*)g,
      (__attribute__((address_space(3))) void*)l, 16, 0, 0);
}

// swizzled tile: LDS[row][slot] (64 cols = 8 slots), slot = chunk ^ (row&7)
__device__ __forceinline__ short8 frag(const short* t, int row, int chunk) {
  return *(const short8*)(t + row * 64 + ((chunk ^ (row & 7)) << 3));
}

// stage ROWS x 64 bf16 tile via global_load_lds (pre-swizzled global source)
template<int ROWS, int W>
__device__ __forceinline__ void stage_tile(short* dst, const short* src,
                                           int stride, int w, int l) {
  #pragma unroll
  for (int c = 0; c < ROWS / 8; c += W) {
    const int cc = c + w;
    const int row0 = cc << 3;
    const int row = row0 + (l >> 3);
    const int ch = (l & 7) ^ (row & 7);
    gl16(src + (size_t)row * stride + (ch << 3), dst + row0 * 64);
  }
}

// ---------------- K0: fp32 -> bf16 hi/lo split -------------------------------
__global__ __launch_bounds__(256) void k_split(const float* __restrict__ src,
                                               short* __restrict__ h,
                                               short* __restrict__ l) {
  const size_t i = ((size_t)blockIdx.x * 256 + threadIdx.x) * 4;
  const float4 f = *(const float4*)(src + i);
  const float ff[4] = {f.x, f.y, f.z, f.w};
  short4v hv, lv;
  #pragma unroll
  for (int j = 0; j < 4; j++) {
    const ushort u = f2bf(ff[j]);
    hv[j] = (short)u;
    lv[j] = (short)f2bf(ff[j] - bf2f(u));
  }
  *(short4v*)(h + i) = hv;
  *(short4v*)(l + i) = lv;
}

// ---------------- K1: qkv = x @ W_qkv^T (+bias), bf16x3 MFMA, 2-phase -------
// q part is pre-scaled by kScale here.
__global__ __launch_bounds__(512) void k_qkv(const short* __restrict__ xh,
                                             const short* __restrict__ xl,
                                             const short* __restrict__ wh,
                                             const short* __restrict__ wl,
                                             const float* __restrict__ bias,
                                             short* __restrict__ qh, short* __restrict__ ql,
                                             short* __restrict__ kh, short* __restrict__ kl,
                                             short* __restrict__ vh, short* __restrict__ vl) {
  __shared__ __align__(16) short sb[2][32768];
  const int bx = blockIdx.x, by = blockIdx.y;
  const int tid = threadIdx.x, w = tid >> 6, lane = tid & 63;
  const int wr = w >> 2, wc = w & 3;
  const short* Asrc_h = xh + (size_t)(by * 128) * kDim;
  const short* Asrc_l = xl + (size_t)(by * 128) * kDim;
  const short* Bsrc_h = wh + (size_t)(bx * 128) * kDim;
  const short* Bsrc_l = wl + (size_t)(bx * 128) * kDim;

  f32x4 acc[4][2] = {};
  {
    short* nb = sb[0];
    stage_tile<128, 8>(nb,          Asrc_h, kDim, w, lane);
    stage_tile<128, 8>(nb + 8192,   Asrc_l, kDim, w, lane);
    stage_tile<128, 8>(nb + 16384,  Bsrc_h, kDim, w, lane);
    stage_tile<128, 8>(nb + 24576,  Bsrc_l, kDim, w, lane);
  }
  int p = 0;
  #pragma unroll 1
  for (int t = 0; t < 12; ++t) {
    __syncthreads();
    if (t < 11) {
      const int k0 = (t + 1) * 64;
      short* nb = sb[p ^ 1];
      stage_tile<128, 8>(nb,         Asrc_h + k0, kDim, w, lane);
      stage_tile<128, 8>(nb + 8192,  Asrc_l + k0, kDim, w, lane);
      stage_tile<128, 8>(nb + 16384, Bsrc_h + k0, kDim, w, lane);
      stage_tile<128, 8>(nb + 24576, Bsrc_l + k0, kDim, w, lane);
    }
    const short* cb = sb[p];
    #pragma unroll
    for (int s = 0; s < 2; ++s) {
      const int ch = (s << 2) + (lane >> 4);
      short8 af[4], alf[4], bf_[2], blf[2];
      #pragma unroll
      for (int i = 0; i < 4; i++) {
        const int ar = wr * 64 + i * 16 + (lane & 15);
        af[i]  = frag(cb, ar, ch);
        alf[i] = frag(cb + 8192, ar, ch);
      }
      #pragma unroll
      for (int j = 0; j < 2; j++) {
        const int br = wc * 32 + j * 16 + (lane & 15);
        bf_[j] = frag(cb + 16384, br, ch);
        blf[j] = frag(cb + 24576, br, ch);
      }
      #pragma unroll
      for (int i = 0; i < 4; i++)
        #pragma unroll
        for (int j = 0; j < 2; j++) {
          acc[i][j] = MFMA(af[i], bf_[j], acc[i][j]);
          acc[i][j] = MFMA(af[i], blf[j], acc[i][j]);
          acc[i][j] = MFMA(alf[i], bf_[j], acc[i][j]);
        }
    }
    p ^= 1;
  }
  #pragma unroll
  for (int j = 0; j < 2; j++) {
    const int col = bx * 128 + wc * 32 + j * 16 + (lane & 15);
    const int part = col / 768;
    const int rem = col - part * 768;
    const int hh = rem >> 6, d = rem & 63;
    short* dh = (part == 0) ? qh : ((part == 1) ? kh : vh);
    short* dl = (part == 0) ? ql : ((part == 1) ? kl : vl);
    const float bv = bias[col];
    const float scl = (part == 0) ? kScale : 1.0f;
    #pragma unroll
    for (int i = 0; i < 4; i++) {
      #pragma unroll
      for (int r = 0; r < 4; r++) {
        const int gr = by * 128 + wr * 64 + i * 16 + ((lane >> 4) << 2) + r;
        const int b = gr >> 10, n = gr & 1023;
        const float val = (acc[i][j][r] + bv) * scl;
        const ushort hu = f2bf(val);
        const size_t idx = (size_t)((b * kH + hh) * kN + n) * 64 + d;
        dh[idx] = (short)hu;
        dl[idx] = (short)f2bf(val - bf2f(hu));
      }
    }
  }
}

// ---------------- K2: gw = softmax(gelu(v @ gp^T)) via MFMA x3 --------------
__global__ __launch_bounds__(512) void k_gw(const short* __restrict__ vh,
                                            const short* __restrict__ vl,
                                            const float* __restrict__ Wgp,
                                            short* __restrict__ gwh,
                                            short* __restrict__ gwl) {
  const int bh = blockIdx.x;
  const int h = bh % kH;
  const int n0 = blockIdx.y << 7;
  const int tid = threadIdx.x, w = tid >> 6, lane = tid & 63;
  __shared__ __align__(16) short gph[4096], gpl[4096];
  {
    const int r = tid >> 3, c = tid & 7;
    float f[8] __attribute__((aligned(16)));
    *(float4*)(f + 0) = *(const float4*)(Wgp + h * 4096 + r * 64 + c * 8);
    *(float4*)(f + 4) = *(const float4*)(Wgp + h * 4096 + r * 64 + c * 8 + 4);
    short8 hh, ll;
    split8(f, hh, ll);
    const int slot = c ^ (r & 7);
    *(short8*)(gph + r * 64 + slot * 8) = hh;
    *(short8*)(gpl + r * 64 + slot * 8) = ll;
  }
  short8 vhf[2], vlf[2];
  const size_t arow = (size_t)(bh * kN + n0 + w * 16 + (lane & 15)) * 64 + ((lane >> 4) << 3);
  vhf[0] = *(const short8*)(vh + arow); vhf[1] = *(const short8*)(vh + arow + 32);
  vlf[0] = *(const short8*)(vl + arow); vlf[1] = *(const short8*)(vl + arow + 32);
  __syncthreads();

  f32x4 aU[4] = {};
  #pragma unroll
  for (int msub = 0; msub < 4; msub++) {
    #pragma unroll
    for (int s = 0; s < 2; s++) {
      const int row = (msub << 4) + (lane & 15);
      const int ch = (s << 2) + (lane >> 4);
      const short8 bh_ = frag(gph, row, ch);
      const short8 bl_ = frag(gpl, row, ch);
      aU[msub] = MFMA(vhf[s], bh_, aU[msub]);
      aU[msub] = MFMA(vhf[s], bl_, aU[msub]);
      aU[msub] = MFMA(vlf[s], bh_, aU[msub]);
    }
  }
  #pragma unroll
  for (int r = 0; r < 4; r++) {
    float u[4];
    #pragma unroll
    for (int m = 0; m < 4; m++) {
      const float a = aU[m][r];
      u[m] = 0.5f * a * (1.0f + erff(a * 0.70710678118654752f));
    }
    float mx = fmaxf(fmaxf(u[0], u[1]), fmaxf(u[2], u[3]));
    #pragma unroll
    for (int msk = 1; msk < 16; msk <<= 1) mx = fmaxf(mx, __shfl_xor(mx, msk));
    float e[4], ssum = 0.f;
    #pragma unroll
    for (int m = 0; m < 4; m++) { e[m] = __expf(u[m] - mx); ssum += e[m]; }
    #pragma unroll
    for (int msk = 1; msk < 16; msk <<= 1) ssum += __shfl_xor(ssum, msk);
    const float inv = 1.0f / ssum;
    const int n = n0 + w * 16 + ((lane >> 4) << 2) + r;
    #pragma unroll
    for (int m = 0; m < 4; m++) {
      const float g = e[m] * inv;
      const ushort hu = f2bf(g);
      const size_t idx = (size_t)(bh * kN + n) * 64 + (m << 4) + (lane & 15);
      gwh[idx] = (short)hu;
      gwl[idx] = (short)f2bf(g - bf2f(hu));
    }
  }
}

// -------- K2b: vtg[bh][d][m] = bf16( rcol[m] * V[m][d] )  (transposed) ------
__global__ __launch_bounds__(256) void k_vt(const short* __restrict__ vh,
                                            const float* __restrict__ rcolv,
                                            short* __restrict__ vtg) {
  const int bh = blockIdx.x;
  const int n0 = blockIdx.y << 6;
  __shared__ short t[64][80];
  const int tid = threadIdx.x;
  {
    const int n = tid >> 2, d0 = (tid & 3) << 4;
    const float rc = rcolv[bh * kN + n0 + n];
    const short8 a = *(const short8*)(vh + (size_t)(bh * kN + n0 + n) * 64 + d0);
    const short8 b = *(const short8*)(vh + (size_t)(bh * kN + n0 + n) * 64 + d0 + 8);
    #pragma unroll
    for (int i = 0; i < 8; ++i) {
      t[d0 + i][n]     = (short)f2bf(bf2f((ushort)a[i]) * rc);
      t[d0 + 8 + i][n] = (short)f2bf(bf2f((ushort)b[i]) * rc);
    }
  }
  __syncthreads();
  const int d = tid >> 2, j0 = (tid & 3) << 4;
  short* dst = vtg + (size_t)bh * 65536 + (size_t)d * 1024 + n0 + j0;
  *(short8*)(dst)     = *(const short8*)(&t[d][j0]);
  *(short8*)(dst + 8) = *(const short8*)(&t[d][j0 + 8]);
}

// ------- K3: rdenom — 256 thr = 2 n-groups x 2 m-halves, lane-local sums ----
__global__ __launch_bounds__(256, 3) void k_denom(const short* __restrict__ qh,
                                                  const short* __restrict__ ql,
                                                  const short* __restrict__ kh,
                                                  const short* __restrict__ kl,
                                                  const short* __restrict__ gwh,
                                                  const short* __restrict__ gwl,
                                                  float* __restrict__ rdenom) {
  const int bh = blockIdx.x;
  const int n0 = blockIdx.y << 6;
  const int tid = threadIdx.x, w = tid >> 6, lane = tid & 63;
  const int lc = lane & 31, hl = lane >> 5;
  const int nw = w & 1, mh = w >> 1;
  __shared__ __align__(16) short sb[32768];  // [2 m-halves][4 arrays][4096]
  __shared__ float part[4][32];
  const short* my = sb + mh * 16384;

  short8 qB[4], qlB[4], gB[4], glB[4];
  {
    const size_t nrow = (size_t)(bh * kN + n0 + nw * 32 + lc) * 64;
    #pragma unroll
    for (int ks = 0; ks < 4; ks++) {
      const int off = ks * 16 + (hl << 3);
      qB[ks]  = *(const short8*)(qh  + nrow + off);
      qlB[ks] = *(const short8*)(ql  + nrow + off);
      gB[ks]  = *(const short8*)(gwh + nrow + off);
      glB[ks] = *(const short8*)(gwl + nrow + off);
    }
  }
  float dsum = 0.f;
  #pragma unroll 1
  for (int t = 0; t < 8; ++t) {
    __syncthreads();
    const size_t mo0 = (size_t)(bh * kN + t * 64) * 64;
    const size_t mo1 = (size_t)(bh * kN + 512 + t * 64) * 64;
    stage_tile<64, 4>(sb,          kh  + mo0, 64, w, lane);
    stage_tile<64, 4>(sb + 4096,   kl  + mo0, 64, w, lane);
    stage_tile<64, 4>(sb + 8192,   gwh + mo0, 64, w, lane);
    stage_tile<64, 4>(sb + 12288,  gwl + mo0, 64, w, lane);
    stage_tile<64, 4>(sb + 16384,  kh  + mo1, 64, w, lane);
    stage_tile<64, 4>(sb + 20480,  kl  + mo1, 64, w, lane);
    stage_tile<64, 4>(sb + 24576,  gwh + mo1, 64, w, lane);
    stage_tile<64, 4>(sb + 28672,  gwl + mo1, 64, w, lane);
    __syncthreads();
    #pragma unroll
    for (int at = 0; at < 2; ++at) {
      f32x16 aS = {}, aG = {};
      #pragma unroll
      for (int ks = 0; ks < 4; ++ks) {
        const int row = at * 32 + lc;
        const int ck = ks * 2 + hl;
        const short8 Ah_ = frag(my, row, ck);
        const short8 Al_ = frag(my + 4096, row, ck);
        const short8 Eh_ = frag(my + 8192, row, ck);
        const short8 El_ = frag(my + 12288, row, ck);
        aS = MFMA32(Ah_, qB[ks], aS);
        aS = MFMA32(Al_, qB[ks], aS);
        aS = MFMA32(Ah_, qlB[ks], aS);
        aG = MFMA32(Eh_, gB[ks], aG);
        aG = MFMA32(El_, gB[ks], aG);
        aG = MFMA32(Eh_, glB[ks], aG);
      }
      #pragma unroll
      for (int r = 0; r < 16; ++r)
        dsum += __expf(aS[r] * aG[r]);
    }
  }
  dsum += __shfl_xor(dsum, 32);
  if (hl == 0) part[w][lc] = dsum;
  __syncthreads();
  if (tid < 64)
    rdenom[bh * kN + n0 + tid] =
        1.0f / (part[tid >> 5][tid & 31] + part[2 + (tid >> 5)][tid & 31]);
}

// ------- K4: rcol — 256 thr = 2 m-groups x 2 n-halves ------------------------
__global__ __launch_bounds__(256, 3) void k_colsum(const short* __restrict__ qh,
                                                   const short* __restrict__ ql,
                                                   const short* __restrict__ kh,
                                                   const short* __restrict__ kl,
                                                   const short* __restrict__ gwh,
                                                   const short* __restrict__ gwl,
                                                   const float* __restrict__ rdenom,
                                                   const float* __restrict__ alpha,
                                                   float* __restrict__ rcolv) {
  const int bh = blockIdx.x;
  const int m0 = blockIdx.y << 6;
  const int tid = threadIdx.x, w = tid >> 6, lane = tid & 63;
  const int lc = lane & 31, hl = lane >> 5;
  const int mw = w & 1, nh = w >> 1;
  __shared__ __align__(16) short sb[32768];
  __shared__ float part[4][32];
  __shared__ float rdl[2][64];
  const short* my = sb + nh * 16384;
  const float ah_ = 1.0f / (1.0f + __expf(-alpha[bh % kH]));
  const float om = 1.0f - ah_;

  short8 kB[4], klB[4], gB[4], glB[4];
  {
    const size_t mrow = (size_t)(bh * kN + m0 + mw * 32 + lc) * 64;
    #pragma unroll
    for (int ks = 0; ks < 4; ks++) {
      const int off = ks * 16 + (hl << 3);
      kB[ks]  = *(const short8*)(kh  + mrow + off);
      klB[ks] = *(const short8*)(kl  + mrow + off);
      gB[ks]  = *(const short8*)(gwh + mrow + off);
      glB[ks] = *(const short8*)(gwl + mrow + off);
    }
  }
  float csum = 0.f;
  #pragma unroll 1
  for (int t = 0; t < 8; ++t) {
    __syncthreads();
    const size_t no0 = (size_t)(bh * kN + t * 64) * 64;
    const size_t no1 = (size_t)(bh * kN + 512 + t * 64) * 64;
    stage_tile<64, 4>(sb,          qh  + no0, 64, w, lane);
    stage_tile<64, 4>(sb + 4096,   ql  + no0, 64, w, lane);
    stage_tile<64, 4>(sb + 8192,   gwh + no0, 64, w, lane);
    stage_tile<64, 4>(sb + 12288,  gwl + no0, 64, w, lane);
    stage_tile<64, 4>(sb + 16384,  qh  + no1, 64, w, lane);
    stage_tile<64, 4>(sb + 20480,  ql  + no1, 64, w, lane);
    stage_tile<64, 4>(sb + 24576,  gwh + no1, 64, w, lane);
    stage_tile<64, 4>(sb + 28672,  gwl + no1, 64, w, lane);
    if (tid < 128)
      rdl[tid >> 6][tid & 63] =
          rdenom[bh * kN + (tid >> 6) * 512 + t * 64 + (tid & 63)];
    __syncthreads();
    #pragma unroll
    for (int at = 0; at < 2; ++at) {
      f32x16 aS = {}, aG = {};
      #pragma unroll
      for (int ks = 0; ks < 4; ++ks) {
        const int row = at * 32 + lc;
        const int ck = ks * 2 + hl;
        const short8 Ah_ = frag(my, row, ck);
        const short8 Al_ = frag(my + 4096, row, ck);
        const short8 Eh_ = frag(my + 8192, row, ck);
        const short8 El_ = frag(my + 12288, row, ck);
        aS = MFMA32(Ah_, kB[ks], aS);
        aS = MFMA32(Al_, kB[ks], aS);
        aS = MFMA32(Ah_, klB[ks], aS);
        aG = MFMA32(Eh_, gB[ks], aG);
        aG = MFMA32(El_, gB[ks], aG);
        aG = MFMA32(Eh_, glB[ks], aG);
      }
      #pragma unroll
      for (int r = 0; r < 16; ++r) {
        const int nr = at * 32 + (r & 3) + ((r >> 2) << 3) + (hl << 2);
        const float g = aG[r];
        csum += om * (__expf(aS[r] * g) * rdl[nh][nr]) + ah_ * g;
      }
    }
  }
  csum += __shfl_xor(csum, 32);
  if (hl == 0) part[w][lc] = csum;
  __syncthreads();
  if (tid < 64)
    rcolv[bh * kN + m0 + tid] =
        1.0f / (part[tid >> 5][tid & 31] + part[2 + (tid >> 5)][tid & 31] + 1e-8f);
}

// ------- K5: ctx — 512 thr = 4 n-groups x 2 m-halves, in-reg P, PV 32x32 ----
__global__ __launch_bounds__(512, 4) void k_out(const short* __restrict__ qh,
                                                const short* __restrict__ ql,
                                                const short* __restrict__ kh,
                                                const short* __restrict__ kl,
                                                const short* __restrict__ vtg,
                                                const short* __restrict__ gwh,
                                                const short* __restrict__ gwl,
                                                const float* __restrict__ rdenom,
                                                const float* __restrict__ alpha,
                                                short* __restrict__ ctxh,
                                                short* __restrict__ ctxl) {
  const int bh = blockIdx.x;
  const int h = bh % kH;
  const int b = bh / kH;
  const int n0 = blockIdx.y << 7;
  const int tid = threadIdx.x, w = tid >> 6, lane = tid & 63;
  const int lc = lane & 31, hl = lane >> 5;
  const int nw = w & 3, mh = w >> 2;
  __shared__ __align__(16) short sb[40960];  // [2 m-halves][5 arrays][4096] = 80KB
  const float ah_ = 1.0f / (1.0f + __expf(-alpha[h]));
  const float om = 1.0f - ah_;
  const short* my = sb + mh * 20480;

  short8 qB[4], qlB[4], gB[4], glB[4];
  {
    const size_t nrow = (size_t)(bh * kN + n0 + nw * 32 + lc) * 64;
    #pragma unroll
    for (int ks = 0; ks < 4; ks++) {
      const int off = ks * 16 + (hl << 3);
      qB[ks]  = *(const short8*)(qh  + nrow + off);
      qlB[ks] = *(const short8*)(ql  + nrow + off);
      gB[ks]  = *(const short8*)(gwh + nrow + off);
      glB[ks] = *(const short8*)(gwl + nrow + off);
    }
  }
  const float rdn = rdenom[bh * kN + n0 + nw * 32 + lc];
  f32x16 oac[2] = {};

  #pragma unroll 1
  for (int t = 0; t < 8; ++t) {
    __syncthreads();
    const size_t mo0 = (size_t)(bh * kN + t * 64) * 64;
    const size_t mo1 = (size_t)(bh * kN + 512 + t * 64) * 64;
    stage_tile<64, 8>(sb,          kh  + mo0, 64, w, lane);
    stage_tile<64, 8>(sb + 4096,   kl  + mo0, 64, w, lane);
    stage_tile<64, 8>(sb + 8192,   gwh + mo0, 64, w, lane);
    stage_tile<64, 8>(sb + 12288,  gwl + mo0, 64, w, lane);
    stage_tile<64, 8>(sb + 16384,  vtg + (size_t)bh * 65536 + t * 64, kN, w, lane);
    stage_tile<64, 8>(sb + 20480,  kh  + mo1, 64, w, lane);
    stage_tile<64, 8>(sb + 24576,  kl  + mo1, 64, w, lane);
    stage_tile<64, 8>(sb + 28672,  gwh + mo1, 64, w, lane);
    stage_tile<64, 8>(sb + 32768,  gwl + mo1, 64, w, lane);
    stage_tile<64, 8>(sb + 36864,  vtg + (size_t)bh * 65536 + 512 + t * 64, kN, w, lane);
    __syncthreads();
    short8 pf[4];
    #pragma unroll
    for (int at = 0; at < 2; ++at) {
      f32x16 aS = {}, aG = {};
      #pragma unroll
      for (int ks = 0; ks < 4; ++ks) {
        const int row = at * 32 + lc;
        const int ck = ks * 2 + hl;
        const short8 Ah_ = frag(my, row, ck);
        const short8 Al_ = frag(my + 4096, row, ck);
        const short8 Eh_ = frag(my + 8192, row, ck);
        const short8 El_ = frag(my + 12288, row, ck);
        aS = MFMA32(Ah_, qB[ks], aS);
        aS = MFMA32(Al_, qB[ks], aS);
        aS = MFMA32(Ah_, qlB[ks], aS);
        aG = MFMA32(Eh_, gB[ks], aG);
        aG = MFMA32(El_, gB[ks], aG);
        aG = MFMA32(Eh_, glB[ks], aG);
      }
      float a[16];
      #pragma unroll
      for (int r = 0; r < 16; ++r) {
        const float g = aG[r];
        const float p = __expf(aS[r] * g) * rdn;
        a[r] = om * p + ah_ * g;
      }
      uint W[8], Ws[8];
      #pragma unroll
      for (int j = 0; j < 8; ++j) W[j] = packbf(a[2 * j], a[2 * j + 1]);
      #pragma unroll
      for (int j = 0; j < 8; ++j) Ws[j] = __shfl_xor(W[j], 32);
      {
        uint4v b0, b1;
        b0[0] = hl ? Ws[2] : W[0];  b0[1] = hl ? Ws[3] : W[1];
        b0[2] = hl ? W[2]  : Ws[0]; b0[3] = hl ? W[3]  : Ws[1];
        b1[0] = hl ? Ws[6] : W[4];  b1[1] = hl ? Ws[7] : W[5];
        b1[2] = hl ? W[6]  : Ws[4]; b1[3] = hl ? W[7]  : Ws[5];
        pf[at * 2 + 0] = __builtin_bit_cast(short8, b0);
        pf[at * 2 + 1] = __builtin_bit_cast(short8, b1);
      }
    }
    // PV: O^T[d, n] += V'^T[d, m] * P^T[m, n]   (this wave's m-half only)
    #pragma unroll
    for (int dt = 0; dt < 2; ++dt)
      #pragma unroll
      for (int ks = 0; ks < 4; ++ks) {
        const short8 va = frag(my + 16384, dt * 32 + lc, ks * 2 + hl);
        oac[dt] = MFMA32(va, pf[ks], oac[dt]);
      }
  }
  // epilogue: cross-m-half add + transpose via LDS, store ctx hi/lo
  __syncthreads();
  float* buf = (float*)sb;  // [128][68] floats = 34.8KB
  if (mh == 1) {
    #pragma unroll
    for (int dt = 0; dt < 2; ++dt)
      #pragma unroll
      for (int r = 0; r < 16; ++r) {
        const int d = dt * 32 + (r & 3) + ((r >> 2) << 3) + (hl << 2);
        buf[(nw * 32 + lc) * 68 + d] = oac[dt][r];
      }
  }
  __syncthreads();
  if (mh == 0) {
    #pragma unroll
    for (int dt = 0; dt < 2; ++dt)
      #pragma unroll
      for (int r = 0; r < 16; ++r) {
        const int d = dt * 32 + (r & 3) + ((r >> 2) << 3) + (hl << 2);
        const int idx = (nw * 32 + lc) * 68 + d;
        buf[idx] = oac[dt][r] + buf[idx];
      }
  }
  __syncthreads();
  {
    const int rowi = tid >> 2;            // 0..127
    const int d0 = (tid & 3) << 4;        // 0,16,32,48
    float f[16] __attribute__((aligned(16)));
    #pragma unroll
    for (int j = 0; j < 4; ++j)
      *(float4*)(f + 4 * j) = *(const float4*)(&buf[rowi * 68 + d0 + 4 * j]);
    const int n = n0 + rowi;
    short* dsth = ctxh + (size_t)(b * kN + n) * kDim + h * 64 + d0;
    short* dstl = ctxl + (size_t)(b * kN + n) * kDim + h * 64 + d0;
    #pragma unroll
    for (int g8 = 0; g8 < 2; ++g8) {
      short8 hi, lo;
      split8(f + 8 * g8, hi, lo);
      *(short8*)(dsth + 8 * g8) = hi;
      *(short8*)(dstl + 8 * g8) = lo;
    }
  }
}

// ---------------- K6: out = ctx @ W_proj^T + b_proj, bf16x4, 2-phase --------
__global__ __launch_bounds__(512) void k_proj(const short* __restrict__ ch_,
                                              const short* __restrict__ cl_,
                                              const short* __restrict__ wh,
                                              const short* __restrict__ wl,
                                              const float* __restrict__ bias,
                                              float* __restrict__ out) {
  __shared__ __align__(16) short sb[2][32768];
  const int bx = blockIdx.x, by = blockIdx.y;
  const int tid = threadIdx.x, w = tid >> 6, lane = tid & 63;
  const int wr = w >> 2, wc = w & 3;
  const short* Asrc_h = ch_ + (size_t)(by * 128) * kDim;
  const short* Asrc_l = cl_ + (size_t)(by * 128) * kDim;
  const short* Bsrc_h = wh + (size_t)(bx * 128) * kDim;
  const short* Bsrc_l = wl + (size_t)(bx * 128) * kDim;

  f32x4 acc[4][2] = {};
  {
    short* nb = sb[0];
    stage_tile<128, 8>(nb,         Asrc_h, kDim, w, lane);
    stage_tile<128, 8>(nb + 8192,  Asrc_l, kDim, w, lane);
    stage_tile<128, 8>(nb + 16384, Bsrc_h, kDim, w, lane);
    stage_tile<128, 8>(nb + 24576, Bsrc_l, kDim, w, lane);
  }
  int p = 0;
  #pragma unroll 1
  for (int t = 0; t < 12; ++t) {
    __syncthreads();
    if (t < 11) {
      const int k0 = (t + 1) * 64;
      short* nb = sb[p ^ 1];
      stage_tile<128, 8>(nb,         Asrc_h + k0, kDim, w, lane);
      stage_tile<128, 8>(nb + 8192,  Asrc_l + k0, kDim, w, lane);
      stage_tile<128, 8>(nb + 16384, Bsrc_h + k0, kDim, w, lane);
      stage_tile<128, 8>(nb + 24576, Bsrc_l + k0, kDim, w, lane);
    }
    const short* cb = sb[p];
    #pragma unroll
    for (int s = 0; s < 2; ++s) {
      const int ch = (s << 2) + (lane >> 4);
      short8 af[4], alf[4], bf_[2], blf[2];
      #pragma unroll
      for (int i = 0; i < 4; i++) {
        const int ar = wr * 64 + i * 16 + (lane & 15);
        af[i]  = frag(cb, ar, ch);
        alf[i] = frag(cb + 8192, ar, ch);
      }
      #pragma unroll
      for (int j = 0; j < 2; j++) {
        const int br = wc * 32 + j * 16 + (lane & 15);
        bf_[j] = frag(cb + 16384, br, ch);
        blf[j] = frag(cb + 24576, br, ch);
      }
      #pragma unroll
      for (int i = 0; i < 4; i++)
        #pragma unroll
        for (int j = 0; j < 2; j++) {
          acc[i][j] = MFMA(af[i], bf_[j], acc[i][j]);
          acc[i][j] = MFMA(af[i], blf[j], acc[i][j]);
          acc[i][j] = MFMA(alf[i], bf_[j], acc[i][j]);
          acc[i][j] = MFMA(alf[i], blf[j], acc[i][j]);
        }
    }
    p ^= 1;
  }
  #pragma unroll
  for (int j = 0; j < 2; j++) {
    const int col = bx * 128 + wc * 32 + j * 16 + (lane & 15);
    const float bv = bias[col];
    #pragma unroll
    for (int i = 0; i < 4; i++) {
      #pragma unroll
      for (int r = 0; r < 4; r++) {
        const int row = by * 128 + wr * 64 + i * 16 + ((lane >> 4) << 2) + r;
        out[(size_t)row * kDim + col] = acc[i][j][r] + bv;
      }
    }
  }
}

}  // namespace

extern "C" void kernel_launch(void* const* d_in, const int* in_sizes, int n_in,
                              void* d_out, int out_size, void* d_ws, size_t ws_size,
                              hipStream_t stream) {
  const float* x     = (const float*)d_in[0];
  const float* Wqkv  = (const float*)d_in[1];
  const float* bqkv  = (const float*)d_in[2];
  const float* Wgp   = (const float*)d_in[3];
  const float* alpha = (const float*)d_in[4];
  const float* Wproj = (const float*)d_in[5];
  const float* bproj = (const float*)d_in[6];
  float* out = (float*)d_out;

  // workspace: 10 bf16 regions of 3,145,728 elems + 2 small fp32 (63.3 MB).
  // Aliases: Wq-split in gw region; vtg in vl region (vl dead after k_gw);
  //          ctx in x region; Wp-split in q region.
  const size_t he = 3145728;
  short* qh  = (short*)d_ws;
  short* ql  = qh + he;
  short* kh  = ql + he;
  short* kl  = kh + he;
  short* vh  = kl + he;
  short* vl  = vh + he;
  short* gwh = vl + he;
  short* gwl = gwh + he;
  short* xh  = gwl + he;
  short* xl  = xh + he;
  float* rdenom = (float*)(xl + he);
  float* rcolv  = rdenom + (size_t)kBH * kN;

  short* Wqh = gwh;  short* Wql = gwl;
  short* vtg = vl;           // [48][64][1024] = rcol-scaled V^T
  short* ctxh = xh;  short* ctxl = xl;
  short* Wph = qh;   short* Wpl = ql;

  k_split<<<3072, 256, 0, stream>>>(x, xh, xl);
  k_split<<<1728, 256, 0, stream>>>(Wqkv, Wqh, Wql);
  k_qkv  <<<dim3(18, 32), 512, 0, stream>>>(xh, xl, Wqh, Wql, bqkv,
                                            qh, ql, kh, kl, vh, vl);
  k_gw   <<<dim3(kBH, 8), 512, 0, stream>>>(vh, vl, Wgp, gwh, gwl);
  k_denom<<<dim3(kBH, 16), 256, 0, stream>>>(qh, ql, kh, kl, gwh, gwl, rdenom);
  k_colsum<<<dim3(kBH, 16), 256, 0, stream>>>(qh, ql, kh, kl, gwh, gwl,
                                              rdenom, alpha, rcolv);
  k_vt   <<<dim3(kBH, 16), 256, 0, stream>>>(vh, rcolv, vtg);
  k_out  <<<dim3(kBH, 8), 512, 0, stream>>>(qh, ql, kh, kl, vtg, gwh, gwl,
                                            rdenom, alpha, ctxh, ctxl);
  k_split<<<576, 256, 0, stream>>>(Wproj, Wph, Wpl);
  k_proj <<<dim3(6, 32), 512, 0, stream>>>(ctxh, ctxl, Wph, Wpl, bproj, out);
}

// Round 8
// 277.835 us; speedup vs baseline: 1.2530x; 1.2530x over previous
//
#include <hip/hip_runtime.h>
#include <math.h>

namespace {

constexpr int kN   = 1024;
constexpr int kDim = 768;
constexpr int kH   = 12;
constexpr int kBH  = 48;
constexpr float kScale = 0.125f;  // HD^-0.5 (folded into q at k_qkv)

typedef __attribute__((ext_vector_type(8))) short short8;
typedef __attribute__((ext_vector_type(4))) short short4v;
typedef __attribute__((ext_vector_type(4))) float f32x4;
typedef __attribute__((ext_vector_type(16))) float f32x16;
typedef __attribute__((ext_vector_type(4))) uint uint4v;

#define MFMA(a, b, c)   __builtin_amdgcn_mfma_f32_16x16x32_bf16(a, b, c, 0, 0, 0)
#define MFMA32(a, b, c) __builtin_amdgcn_mfma_f32_32x32x16_bf16(a, b, c, 0, 0, 0)

// ---------- bf16 helpers (round-to-nearest-even) ----------
__device__ __forceinline__ ushort f2bf(float f) {
  uint u = __builtin_bit_cast(uint, f);
  u += 0x7fffu + ((u >> 16) & 1u);
  return (ushort)(u >> 16);
}
__device__ __forceinline__ float bf2f(ushort h) {
  uint u = ((uint)h) << 16;
  return __builtin_bit_cast(float, u);
}
__device__ __forceinline__ void split8(const float* f, short8& hi, short8& lo) {
  #pragma unroll
  for (int i = 0; i < 8; i++) {
    const ushort h = f2bf(f[i]);
    hi[i] = (short)h;
    lo[i] = (short)f2bf(f[i] - bf2f(h));
  }
}
__device__ __forceinline__ uint packbf(float a, float b) {
  return (uint)f2bf(a) | ((uint)f2bf(b) << 16);
}

// ---------- async global->LDS, 16B per lane ----------
__device__ __forceinline__ void gl16(const short* g, short* l) {
  __builtin_amdgcn_global_load_lds(
      (const __attribute__((address_space(1))) void*)g,
      (__attribute__((address_space(3))) void*)l, 16, 0, 0);
}

// swizzled tile: LDS[row][slot] (64 cols = 8 slots), slot = chunk ^ (row&7)
__device__ __forceinline__ short8 frag(const short* t, int row, int chunk) {
  return *(const short8*)(t + row * 64 + ((chunk ^ (row & 7)) << 3));
}

// stage ROWS x 64 bf16 tile via global_load_lds (pre-swizzled global source)
template<int ROWS, int W>
__device__ __forceinline__ void stage_tile(short* dst, const short* src,
                                           int stride, int w, int l) {
  #pragma unroll
  for (int c = 0; c < ROWS / 8; c += W) {
    const int cc = c + w;
    const int row0 = cc << 3;
    const int row = row0 + (l >> 3);
    const int ch = (l & 7) ^ (row & 7);
    gl16(src + (size_t)row * stride + (ch << 3), dst + row0 * 64);
  }
}

// ---------------- K0: fp32 -> bf16 hi/lo split -------------------------------
__global__ __launch_bounds__(256) void k_split(const float* __restrict__ src,
                                               short* __restrict__ h,
                                               short* __restrict__ l) {
  const size_t i = ((size_t)blockIdx.x * 256 + threadIdx.x) * 4;
  const float4 f = *(const float4*)(src + i);
  const float ff[4] = {f.x, f.y, f.z, f.w};
  short4v hv, lv;
  #pragma unroll
  for (int j = 0; j < 4; j++) {
    const ushort u = f2bf(ff[j]);
    hv[j] = (short)u;
    lv[j] = (short)f2bf(ff[j] - bf2f(u));
  }
  *(short4v*)(h + i) = hv;
  *(short4v*)(l + i) = lv;
}

// ---------------- K1: qkv = x @ W_qkv^T (+bias), bf16x3 MFMA, 2-phase -------
// q part is pre-scaled by kScale here.
__global__ __launch_bounds__(512) void k_qkv(const short* __restrict__ xh,
                                             const short* __restrict__ xl,
                                             const short* __restrict__ wh,
                                             const short* __restrict__ wl,
                                             const float* __restrict__ bias,
                                             short* __restrict__ qh, short* __restrict__ ql,
                                             short* __restrict__ kh, short* __restrict__ kl,
                                             short* __restrict__ vh, short* __restrict__ vl) {
  __shared__ __align__(16) short sb[2][32768];
  const int bx = blockIdx.x, by = blockIdx.y;
  const int tid = threadIdx.x, w = tid >> 6, lane = tid & 63;
  const int wr = w >> 2, wc = w & 3;
  const short* Asrc_h = xh + (size_t)(by * 128) * kDim;
  const short* Asrc_l = xl + (size_t)(by * 128) * kDim;
  const short* Bsrc_h = wh + (size_t)(bx * 128) * kDim;
  const short* Bsrc_l = wl + (size_t)(bx * 128) * kDim;

  f32x4 acc[4][2] = {};
  {
    short* nb = sb[0];
    stage_tile<128, 8>(nb,          Asrc_h, kDim, w, lane);
    stage_tile<128, 8>(nb + 8192,   Asrc_l, kDim, w, lane);
    stage_tile<128, 8>(nb + 16384,  Bsrc_h, kDim, w, lane);
    stage_tile<128, 8>(nb + 24576,  Bsrc_l, kDim, w, lane);
  }
  int p = 0;
  #pragma unroll 1
  for (int t = 0; t < 12; ++t) {
    __syncthreads();
    if (t < 11) {
      const int k0 = (t + 1) * 64;
      short* nb = sb[p ^ 1];
      stage_tile<128, 8>(nb,         Asrc_h + k0, kDim, w, lane);
      stage_tile<128, 8>(nb + 8192,  Asrc_l + k0, kDim, w, lane);
      stage_tile<128, 8>(nb + 16384, Bsrc_h + k0, kDim, w, lane);
      stage_tile<128, 8>(nb + 24576, Bsrc_l + k0, kDim, w, lane);
    }
    const short* cb = sb[p];
    #pragma unroll
    for (int s = 0; s < 2; ++s) {
      const int ch = (s << 2) + (lane >> 4);
      short8 af[4], alf[4], bf_[2], blf[2];
      #pragma unroll
      for (int i = 0; i < 4; i++) {
        const int ar = wr * 64 + i * 16 + (lane & 15);
        af[i]  = frag(cb, ar, ch);
        alf[i] = frag(cb + 8192, ar, ch);
      }
      #pragma unroll
      for (int j = 0; j < 2; j++) {
        const int br = wc * 32 + j * 16 + (lane & 15);
        bf_[j] = frag(cb + 16384, br, ch);
        blf[j] = frag(cb + 24576, br, ch);
      }
      #pragma unroll
      for (int i = 0; i < 4; i++)
        #pragma unroll
        for (int j = 0; j < 2; j++) {
          acc[i][j] = MFMA(af[i], bf_[j], acc[i][j]);
          acc[i][j] = MFMA(af[i], blf[j], acc[i][j]);
          acc[i][j] = MFMA(alf[i], bf_[j], acc[i][j]);
        }
    }
    p ^= 1;
  }
  #pragma unroll
  for (int j = 0; j < 2; j++) {
    const int col = bx * 128 + wc * 32 + j * 16 + (lane & 15);
    const int part = col / 768;
    const int rem = col - part * 768;
    const int hh = rem >> 6, d = rem & 63;
    short* dh = (part == 0) ? qh : ((part == 1) ? kh : vh);
    short* dl = (part == 0) ? ql : ((part == 1) ? kl : vl);
    const float bv = bias[col];
    const float scl = (part == 0) ? kScale : 1.0f;
    #pragma unroll
    for (int i = 0; i < 4; i++) {
      #pragma unroll
      for (int r = 0; r < 4; r++) {
        const int gr = by * 128 + wr * 64 + i * 16 + ((lane >> 4) << 2) + r;
        const int b = gr >> 10, n = gr & 1023;
        const float val = (acc[i][j][r] + bv) * scl;
        const ushort hu = f2bf(val);
        const size_t idx = (size_t)((b * kH + hh) * kN + n) * 64 + d;
        dh[idx] = (short)hu;
        dl[idx] = (short)f2bf(val - bf2f(hu));
      }
    }
  }
}

// ---------------- K2: gw = softmax(gelu(v @ gp^T)) via MFMA x3 --------------
__global__ __launch_bounds__(512) void k_gw(const short* __restrict__ vh,
                                            const short* __restrict__ vl,
                                            const float* __restrict__ Wgp,
                                            short* __restrict__ gwh,
                                            short* __restrict__ gwl) {
  const int bh = blockIdx.x;
  const int h = bh % kH;
  const int n0 = blockIdx.y << 7;
  const int tid = threadIdx.x, w = tid >> 6, lane = tid & 63;
  __shared__ __align__(16) short gph[4096], gpl[4096];
  {
    const int r = tid >> 3, c = tid & 7;
    float f[8] __attribute__((aligned(16)));
    *(float4*)(f + 0) = *(const float4*)(Wgp + h * 4096 + r * 64 + c * 8);
    *(float4*)(f + 4) = *(const float4*)(Wgp + h * 4096 + r * 64 + c * 8 + 4);
    short8 hh, ll;
    split8(f, hh, ll);
    const int slot = c ^ (r & 7);
    *(short8*)(gph + r * 64 + slot * 8) = hh;
    *(short8*)(gpl + r * 64 + slot * 8) = ll;
  }
  short8 vhf[2], vlf[2];
  const size_t arow = (size_t)(bh * kN + n0 + w * 16 + (lane & 15)) * 64 + ((lane >> 4) << 3);
  vhf[0] = *(const short8*)(vh + arow); vhf[1] = *(const short8*)(vh + arow + 32);
  vlf[0] = *(const short8*)(vl + arow); vlf[1] = *(const short8*)(vl + arow + 32);
  __syncthreads();

  f32x4 aU[4] = {};
  #pragma unroll
  for (int msub = 0; msub < 4; msub++) {
    #pragma unroll
    for (int s = 0; s < 2; s++) {
      const int row = (msub << 4) + (lane & 15);
      const int ch = (s << 2) + (lane >> 4);
      const short8 bh_ = frag(gph, row, ch);
      const short8 bl_ = frag(gpl, row, ch);
      aU[msub] = MFMA(vhf[s], bh_, aU[msub]);
      aU[msub] = MFMA(vhf[s], bl_, aU[msub]);
      aU[msub] = MFMA(vlf[s], bh_, aU[msub]);
    }
  }
  #pragma unroll
  for (int r = 0; r < 4; r++) {
    float u[4];
    #pragma unroll
    for (int m = 0; m < 4; m++) {
      const float a = aU[m][r];
      u[m] = 0.5f * a * (1.0f + erff(a * 0.70710678118654752f));
    }
    float mx = fmaxf(fmaxf(u[0], u[1]), fmaxf(u[2], u[3]));
    #pragma unroll
    for (int msk = 1; msk < 16; msk <<= 1) mx = fmaxf(mx, __shfl_xor(mx, msk));
    float e[4], ssum = 0.f;
    #pragma unroll
    for (int m = 0; m < 4; m++) { e[m] = __expf(u[m] - mx); ssum += e[m]; }
    #pragma unroll
    for (int msk = 1; msk < 16; msk <<= 1) ssum += __shfl_xor(ssum, msk);
    const float inv = 1.0f / ssum;
    const int n = n0 + w * 16 + ((lane >> 4) << 2) + r;
    #pragma unroll
    for (int m = 0; m < 4; m++) {
      const float g = e[m] * inv;
      const ushort hu = f2bf(g);
      const size_t idx = (size_t)(bh * kN + n) * 64 + (m << 4) + (lane & 15);
      gwh[idx] = (short)hu;
      gwl[idx] = (short)f2bf(g - bf2f(hu));
    }
  }
}

// -------- K2b: vtg[bh][d][m] = bf16( rcol[m] * V[m][d] )  (transposed) ------
__global__ __launch_bounds__(256) void k_vt(const short* __restrict__ vh,
                                            const float* __restrict__ rcolv,
                                            short* __restrict__ vtg) {
  const int bh = blockIdx.x;
  const int n0 = blockIdx.y << 6;
  __shared__ short t[64][80];
  const int tid = threadIdx.x;
  {
    const int n = tid >> 2, d0 = (tid & 3) << 4;
    const float rc = rcolv[bh * kN + n0 + n];
    const short8 a = *(const short8*)(vh + (size_t)(bh * kN + n0 + n) * 64 + d0);
    const short8 b = *(const short8*)(vh + (size_t)(bh * kN + n0 + n) * 64 + d0 + 8);
    #pragma unroll
    for (int i = 0; i < 8; ++i) {
      t[d0 + i][n]     = (short)f2bf(bf2f((ushort)a[i]) * rc);
      t[d0 + 8 + i][n] = (short)f2bf(bf2f((ushort)b[i]) * rc);
    }
  }
  __syncthreads();
  const int d = tid >> 2, j0 = (tid & 3) << 4;
  short* dst = vtg + (size_t)bh * 65536 + (size_t)d * 1024 + n0 + j0;
  *(short8*)(dst)     = *(const short8*)(&t[d][j0]);
  *(short8*)(dst + 8) = *(const short8*)(&t[d][j0 + 8]);
}

// ------- K3: rdenom — 256 thr = 2 n-groups x 2 m-halves, lane-local sums ----
__global__ __launch_bounds__(256, 3) void k_denom(const short* __restrict__ qh,
                                                  const short* __restrict__ ql,
                                                  const short* __restrict__ kh,
                                                  const short* __restrict__ kl,
                                                  const short* __restrict__ gwh,
                                                  const short* __restrict__ gwl,
                                                  float* __restrict__ rdenom) {
  const int bh = blockIdx.x;
  const int n0 = blockIdx.y << 6;
  const int tid = threadIdx.x, w = tid >> 6, lane = tid & 63;
  const int lc = lane & 31, hl = lane >> 5;
  const int nw = w & 1, mh = w >> 1;
  __shared__ __align__(16) short sb[32768];  // [2 m-halves][4 arrays][4096]
  __shared__ float part[4][32];
  const short* my = sb + mh * 16384;

  short8 qB[4], qlB[4], gB[4], glB[4];
  {
    const size_t nrow = (size_t)(bh * kN + n0 + nw * 32 + lc) * 64;
    #pragma unroll
    for (int ks = 0; ks < 4; ks++) {
      const int off = ks * 16 + (hl << 3);
      qB[ks]  = *(const short8*)(qh  + nrow + off);
      qlB[ks] = *(const short8*)(ql  + nrow + off);
      gB[ks]  = *(const short8*)(gwh + nrow + off);
      glB[ks] = *(const short8*)(gwl + nrow + off);
    }
  }
  float dsum = 0.f;
  #pragma unroll 1
  for (int t = 0; t < 8; ++t) {
    __syncthreads();
    const size_t mo0 = (size_t)(bh * kN + t * 64) * 64;
    const size_t mo1 = (size_t)(bh * kN + 512 + t * 64) * 64;
    stage_tile<64, 4>(sb,          kh  + mo0, 64, w, lane);
    stage_tile<64, 4>(sb + 4096,   kl  + mo0, 64, w, lane);
    stage_tile<64, 4>(sb + 8192,   gwh + mo0, 64, w, lane);
    stage_tile<64, 4>(sb + 12288,  gwl + mo0, 64, w, lane);
    stage_tile<64, 4>(sb + 16384,  kh  + mo1, 64, w, lane);
    stage_tile<64, 4>(sb + 20480,  kl  + mo1, 64, w, lane);
    stage_tile<64, 4>(sb + 24576,  gwh + mo1, 64, w, lane);
    stage_tile<64, 4>(sb + 28672,  gwl + mo1, 64, w, lane);
    __syncthreads();
    #pragma unroll
    for (int at = 0; at < 2; ++at) {
      f32x16 aS = {}, aG = {};
      #pragma unroll
      for (int ks = 0; ks < 4; ++ks) {
        const int row = at * 32 + lc;
        const int ck = ks * 2 + hl;
        const short8 Ah_ = frag(my, row, ck);
        const short8 Al_ = frag(my + 4096, row, ck);
        const short8 Eh_ = frag(my + 8192, row, ck);
        const short8 El_ = frag(my + 12288, row, ck);
        aS = MFMA32(Ah_, qB[ks], aS);
        aS = MFMA32(Al_, qB[ks], aS);
        aS = MFMA32(Ah_, qlB[ks], aS);
        aG = MFMA32(Eh_, gB[ks], aG);
        aG = MFMA32(El_, gB[ks], aG);
        aG = MFMA32(Eh_, glB[ks], aG);
      }
      #pragma unroll
      for (int r = 0; r < 16; ++r)
        dsum += __expf(aS[r] * aG[r]);
    }
  }
  dsum += __shfl_xor(dsum, 32);
  if (hl == 0) part[w][lc] = dsum;
  __syncthreads();
  if (tid < 64)
    rdenom[bh * kN + n0 + tid] =
        1.0f / (part[tid >> 5][tid & 31] + part[2 + (tid >> 5)][tid & 31]);
}

// ------- K4: rcol — 256 thr = 2 m-groups x 2 n-halves ------------------------
__global__ __launch_bounds__(256, 3) void k_colsum(const short* __restrict__ qh,
                                                   const short* __restrict__ ql,
                                                   const short* __restrict__ kh,
                                                   const short* __restrict__ kl,
                                                   const short* __restrict__ gwh,
                                                   const short* __restrict__ gwl,
                                                   const float* __restrict__ rdenom,
                                                   const float* __restrict__ alpha,
                                                   float* __restrict__ rcolv) {
  const int bh = blockIdx.x;
  const int m0 = blockIdx.y << 6;
  const int tid = threadIdx.x, w = tid >> 6, lane = tid & 63;
  const int lc = lane & 31, hl = lane >> 5;
  const int mw = w & 1, nh = w >> 1;
  __shared__ __align__(16) short sb[32768];
  __shared__ float part[4][32];
  __shared__ float rdl[2][64];
  const short* my = sb + nh * 16384;
  const float ah_ = 1.0f / (1.0f + __expf(-alpha[bh % kH]));
  const float om = 1.0f - ah_;

  short8 kB[4], klB[4], gB[4], glB[4];
  {
    const size_t mrow = (size_t)(bh * kN + m0 + mw * 32 + lc) * 64;
    #pragma unroll
    for (int ks = 0; ks < 4; ks++) {
      const int off = ks * 16 + (hl << 3);
      kB[ks]  = *(const short8*)(kh  + mrow + off);
      klB[ks] = *(const short8*)(kl  + mrow + off);
      gB[ks]  = *(const short8*)(gwh + mrow + off);
      glB[ks] = *(const short8*)(gwl + mrow + off);
    }
  }
  float csum = 0.f;
  #pragma unroll 1
  for (int t = 0; t < 8; ++t) {
    __syncthreads();
    const size_t no0 = (size_t)(bh * kN + t * 64) * 64;
    const size_t no1 = (size_t)(bh * kN + 512 + t * 64) * 64;
    stage_tile<64, 4>(sb,          qh  + no0, 64, w, lane);
    stage_tile<64, 4>(sb + 4096,   ql  + no0, 64, w, lane);
    stage_tile<64, 4>(sb + 8192,   gwh + no0, 64, w, lane);
    stage_tile<64, 4>(sb + 12288,  gwl + no0, 64, w, lane);
    stage_tile<64, 4>(sb + 16384,  qh  + no1, 64, w, lane);
    stage_tile<64, 4>(sb + 20480,  ql  + no1, 64, w, lane);
    stage_tile<64, 4>(sb + 24576,  gwh + no1, 64, w, lane);
    stage_tile<64, 4>(sb + 28672,  gwl + no1, 64, w, lane);
    if (tid < 128)
      rdl[tid >> 6][tid & 63] =
          rdenom[bh * kN + (tid >> 6) * 512 + t * 64 + (tid & 63)];
    __syncthreads();
    #pragma unroll
    for (int at = 0; at < 2; ++at) {
      f32x16 aS = {}, aG = {};
      #pragma unroll
      for (int ks = 0; ks < 4; ++ks) {
        const int row = at * 32 + lc;
        const int ck = ks * 2 + hl;
        const short8 Ah_ = frag(my, row, ck);
        const short8 Al_ = frag(my + 4096, row, ck);
        const short8 Eh_ = frag(my + 8192, row, ck);
        const short8 El_ = frag(my + 12288, row, ck);
        aS = MFMA32(Ah_, kB[ks], aS);
        aS = MFMA32(Al_, kB[ks], aS);
        aS = MFMA32(Ah_, klB[ks], aS);
        aG = MFMA32(Eh_, gB[ks], aG);
        aG = MFMA32(El_, gB[ks], aG);
        aG = MFMA32(Eh_, glB[ks], aG);
      }
      #pragma unroll
      for (int r = 0; r < 16; ++r) {
        const int nr = at * 32 + (r & 3) + ((r >> 2) << 3) + (hl << 2);
        const float g = aG[r];
        csum += om * (__expf(aS[r] * g) * rdl[nh][nr]) + ah_ * g;
      }
    }
  }
  csum += __shfl_xor(csum, 32);
  if (hl == 0) part[w][lc] = csum;
  __syncthreads();
  if (tid < 64)
    rcolv[bh * kN + m0 + tid] =
        1.0f / (part[tid >> 5][tid & 31] + part[2 + (tid >> 5)][tid & 31] + 1e-8f);
}

// ------- K5: ctx — 512 thr = 4 n-groups x 2 m-halves, in-reg P, PV 32x32 ----
// launch_bounds (512, 2): VGPR cap 256 — R7's (512,4) capped at 64 and spilled.
__global__ __launch_bounds__(512, 2) void k_out(const short* __restrict__ qh,
                                                const short* __restrict__ ql,
                                                const short* __restrict__ kh,
                                                const short* __restrict__ kl,
                                                const short* __restrict__ vtg,
                                                const short* __restrict__ gwh,
                                                const short* __restrict__ gwl,
                                                const float* __restrict__ rdenom,
                                                const float* __restrict__ alpha,
                                                short* __restrict__ ctxh,
                                                short* __restrict__ ctxl) {
  const int bh = blockIdx.x;
  const int h = bh % kH;
  const int b = bh / kH;
  const int n0 = blockIdx.y << 7;
  const int tid = threadIdx.x, w = tid >> 6, lane = tid & 63;
  const int lc = lane & 31, hl = lane >> 5;
  const int nw = w & 3, mh = w >> 2;
  __shared__ __align__(16) short sb[40960];  // [2 m-halves][5 arrays][4096] = 80KB
  const float ah_ = 1.0f / (1.0f + __expf(-alpha[h]));
  const float om = 1.0f - ah_;
  const short* my = sb + mh * 20480;

  short8 qB[4], qlB[4], gB[4], glB[4];
  {
    const size_t nrow = (size_t)(bh * kN + n0 + nw * 32 + lc) * 64;
    #pragma unroll
    for (int ks = 0; ks < 4; ks++) {
      const int off = ks * 16 + (hl << 3);
      qB[ks]  = *(const short8*)(qh  + nrow + off);
      qlB[ks] = *(const short8*)(ql  + nrow + off);
      gB[ks]  = *(const short8*)(gwh + nrow + off);
      glB[ks] = *(const short8*)(gwl + nrow + off);
    }
  }
  const float rdn = rdenom[bh * kN + n0 + nw * 32 + lc];
  f32x16 oac[2] = {};

  #pragma unroll 1
  for (int t = 0; t < 8; ++t) {
    __syncthreads();
    const size_t mo0 = (size_t)(bh * kN + t * 64) * 64;
    const size_t mo1 = (size_t)(bh * kN + 512 + t * 64) * 64;
    stage_tile<64, 8>(sb,          kh  + mo0, 64, w, lane);
    stage_tile<64, 8>(sb + 4096,   kl  + mo0, 64, w, lane);
    stage_tile<64, 8>(sb + 8192,   gwh + mo0, 64, w, lane);
    stage_tile<64, 8>(sb + 12288,  gwl + mo0, 64, w, lane);
    stage_tile<64, 8>(sb + 16384,  vtg + (size_t)bh * 65536 + t * 64, kN, w, lane);
    stage_tile<64, 8>(sb + 20480,  kh  + mo1, 64, w, lane);
    stage_tile<64, 8>(sb + 24576,  kl  + mo1, 64, w, lane);
    stage_tile<64, 8>(sb + 28672,  gwh + mo1, 64, w, lane);
    stage_tile<64, 8>(sb + 32768,  gwl + mo1, 64, w, lane);
    stage_tile<64, 8>(sb + 36864,  vtg + (size_t)bh * 65536 + 512 + t * 64, kN, w, lane);
    __syncthreads();
    short8 pf[4];
    #pragma unroll
    for (int at = 0; at < 2; ++at) {
      f32x16 aS = {}, aG = {};
      #pragma unroll
      for (int ks = 0; ks < 4; ++ks) {
        const int row = at * 32 + lc;
        const int ck = ks * 2 + hl;
        const short8 Ah_ = frag(my, row, ck);
        const short8 Al_ = frag(my + 4096, row, ck);
        const short8 Eh_ = frag(my + 8192, row, ck);
        const short8 El_ = frag(my + 12288, row, ck);
        aS = MFMA32(Ah_, qB[ks], aS);
        aS = MFMA32(Al_, qB[ks], aS);
        aS = MFMA32(Ah_, qlB[ks], aS);
        aG = MFMA32(Eh_, gB[ks], aG);
        aG = MFMA32(El_, gB[ks], aG);
        aG = MFMA32(Eh_, glB[ks], aG);
      }
      float a[16];
      #pragma unroll
      for (int r = 0; r < 16; ++r) {
        const float g = aG[r];
        const float p = __expf(aS[r] * g) * rdn;
        a[r] = om * p + ah_ * g;
      }
      uint W[8], Ws[8];
      #pragma unroll
      for (int j = 0; j < 8; ++j) W[j] = packbf(a[2 * j], a[2 * j + 1]);
      #pragma unroll
      for (int j = 0; j < 8; ++j) Ws[j] = __shfl_xor(W[j], 32);
      {
        uint4v b0, b1;
        b0[0] = hl ? Ws[2] : W[0];  b0[1] = hl ? Ws[3] : W[1];
        b0[2] = hl ? W[2]  : Ws[0]; b0[3] = hl ? W[3]  : Ws[1];
        b1[0] = hl ? Ws[6] : W[4];  b1[1] = hl ? Ws[7] : W[5];
        b1[2] = hl ? W[6]  : Ws[4]; b1[3] = hl ? W[7]  : Ws[5];
        pf[at * 2 + 0] = __builtin_bit_cast(short8, b0);
        pf[at * 2 + 1] = __builtin_bit_cast(short8, b1);
      }
    }
    // PV: O^T[d, n] += V'^T[d, m] * P^T[m, n]   (this wave's m-half only)
    #pragma unroll
    for (int dt = 0; dt < 2; ++dt)
      #pragma unroll
      for (int ks = 0; ks < 4; ++ks) {
        const short8 va = frag(my + 16384, dt * 32 + lc, ks * 2 + hl);
        oac[dt] = MFMA32(va, pf[ks], oac[dt]);
      }
  }
  // epilogue: cross-m-half add + transpose via LDS, store ctx hi/lo
  __syncthreads();
  float* buf = (float*)sb;  // [128][68] floats = 34.8KB
  if (mh == 1) {
    #pragma unroll
    for (int dt = 0; dt < 2; ++dt)
      #pragma unroll
      for (int r = 0; r < 16; ++r) {
        const int d = dt * 32 + (r & 3) + ((r >> 2) << 3) + (hl << 2);
        buf[(nw * 32 + lc) * 68 + d] = oac[dt][r];
      }
  }
  __syncthreads();
  if (mh == 0) {
    #pragma unroll
    for (int dt = 0; dt < 2; ++dt)
      #pragma unroll
      for (int r = 0; r < 16; ++r) {
        const int d = dt * 32 + (r & 3) + ((r >> 2) << 3) + (hl << 2);
        const int idx = (nw * 32 + lc) * 68 + d;
        buf[idx] = oac[dt][r] + buf[idx];
      }
  }
  __syncthreads();
  {
    const int rowi = tid >> 2;            // 0..127
    const int d0 = (tid & 3) << 4;        // 0,16,32,48
    float f[16] __attribute__((aligned(16)));
    #pragma unroll
    for (int j = 0; j < 4; ++j)
      *(float4*)(f + 4 * j) = *(const float4*)(&buf[rowi * 68 + d0 + 4 * j]);
    const int n = n0 + rowi;
    short* dsth = ctxh + (size_t)(b * kN + n) * kDim + h * 64 + d0;
    short* dstl = ctxl + (size_t)(b * kN + n) * kDim + h * 64 + d0;
    #pragma unroll
    for (int g8 = 0; g8 < 2; ++g8) {
      short8 hi, lo;
      split8(f + 8 * g8, hi, lo);
      *(short8*)(dsth + 8 * g8) = hi;
      *(short8*)(dstl + 8 * g8) = lo;
    }
  }
}

// ---------------- K6: out = ctx @ W_proj^T + b_proj, bf16x4, 2-phase --------
__global__ __launch_bounds__(512) void k_proj(const short* __restrict__ ch_,
                                              const short* __restrict__ cl_,
                                              const short* __restrict__ wh,
                                              const short* __restrict__ wl,
                                              const float* __restrict__ bias,
                                              float* __restrict__ out) {
  __shared__ __align__(16) short sb[2][32768];
  const int bx = blockIdx.x, by = blockIdx.y;
  const int tid = threadIdx.x, w = tid >> 6, lane = tid & 63;
  const int wr = w >> 2, wc = w & 3;
  const short* Asrc_h = ch_ + (size_t)(by * 128) * kDim;
  const short* Asrc_l = cl_ + (size_t)(by * 128) * kDim;
  const short* Bsrc_h = wh + (size_t)(bx * 128) * kDim;
  const short* Bsrc_l = wl + (size_t)(bx * 128) * kDim;

  f32x4 acc[4][2] = {};
  {
    short* nb = sb[0];
    stage_tile<128, 8>(nb,         Asrc_h, kDim, w, lane);
    stage_tile<128, 8>(nb + 8192,  Asrc_l, kDim, w, lane);
    stage_tile<128, 8>(nb + 16384, Bsrc_h, kDim, w, lane);
    stage_tile<128, 8>(nb + 24576, Bsrc_l, kDim, w, lane);
  }
  int p = 0;
  #pragma unroll 1
  for (int t = 0; t < 12; ++t) {
    __syncthreads();
    if (t < 11) {
      const int k0 = (t + 1) * 64;
      short* nb = sb[p ^ 1];
      stage_tile<128, 8>(nb,         Asrc_h + k0, kDim, w, lane);
      stage_tile<128, 8>(nb + 8192,  Asrc_l + k0, kDim, w, lane);
      stage_tile<128, 8>(nb + 16384, Bsrc_h + k0, kDim, w, lane);
      stage_tile<128, 8>(nb + 24576, Bsrc_l + k0, kDim, w, lane);
    }
    const short* cb = sb[p];
    #pragma unroll
    for (int s = 0; s < 2; ++s) {
      const int ch = (s << 2) + (lane >> 4);
      short8 af[4], alf[4], bf_[2], blf[2];
      #pragma unroll
      for (int i = 0; i < 4; i++) {
        const int ar = wr * 64 + i * 16 + (lane & 15);
        af[i]  = frag(cb, ar, ch);
        alf[i] = frag(cb + 8192, ar, ch);
      }
      #pragma unroll
      for (int j = 0; j < 2; j++) {
        const int br = wc * 32 + j * 16 + (lane & 15);
        bf_[j] = frag(cb + 16384, br, ch);
        blf[j] = frag(cb + 24576, br, ch);
      }
      #pragma unroll
      for (int i = 0; i < 4; i++)
        #pragma unroll
        for (int j = 0; j < 2; j++) {
          acc[i][j] = MFMA(af[i], bf_[j], acc[i][j]);
          acc[i][j] = MFMA(af[i], blf[j], acc[i][j]);
          acc[i][j] = MFMA(alf[i], bf_[j], acc[i][j]);
          acc[i][j] = MFMA(alf[i], blf[j], acc[i][j]);
        }
    }
    p ^= 1;
  }
  #pragma unroll
  for (int j = 0; j < 2; j++) {
    const int col = bx * 128 + wc * 32 + j * 16 + (lane & 15);
    const float bv = bias[col];
    #pragma unroll
    for (int i = 0; i < 4; i++) {
      #pragma unroll
      for (int r = 0; r < 4; r++) {
        const int row = by * 128 + wr * 64 + i * 16 + ((lane >> 4) << 2) + r;
        out[(size_t)row * kDim + col] = acc[i][j][r] + bv;
      }
    }
  }
}

}  // namespace

extern "C" void kernel_launch(void* const* d_in, const int* in_sizes, int n_in,
                              void* d_out, int out_size, void* d_ws, size_t ws_size,
                              hipStream_t stream) {
  const float* x     = (const float*)d_in[0];
  const float* Wqkv  = (const float*)d_in[1];
  const float* bqkv  = (const float*)d_in[2];
  const float* Wgp   = (const float*)d_in[3];
  const float* alpha = (const float*)d_in[4];
  const float* Wproj = (const float*)d_in[5];
  const float* bproj = (const float*)d_in[6];
  float* out = (float*)d_out;

  // workspace: 10 bf16 regions of 3,145,728 elems + 2 small fp32 (63.3 MB).
  // Aliases: Wq-split in gw region; vtg in vl region (vl dead after k_gw);
  //          ctx in x region; Wp-split in q region.
  const size_t he = 3145728;
  short* qh  = (short*)d_ws;
  short* ql  = qh + he;
  short* kh  = ql + he;
  short* kl  = kh + he;
  short* vh  = kl + he;
  short* vl  = vh + he;
  short* gwh = vl + he;
  short* gwl = gwh + he;
  short* xh  = gwl + he;
  short* xl  = xh + he;
  float* rdenom = (float*)(xl + he);
  float* rcolv  = rdenom + (size_t)kBH * kN;

  short* Wqh = gwh;  short* Wql = gwl;
  short* vtg = vl;           // [48][64][1024] = rcol-scaled V^T
  short* ctxh = xh;  short* ctxl = xl;
  short* Wph = qh;   short* Wpl = ql;

  k_split<<<3072, 256, 0, stream>>>(x, xh, xl);
  k_split<<<1728, 256, 0, stream>>>(Wqkv, Wqh, Wql);
  k_qkv  <<<dim3(18, 32), 512, 0, stream>>>(xh, xl, Wqh, Wql, bqkv,
                                            qh, ql, kh, kl, vh, vl);
  k_gw   <<<dim3(kBH, 8), 512, 0, stream>>>(vh, vl, Wgp, gwh, gwl);
  k_denom<<<dim3(kBH, 16), 256, 0, stream>>>(qh, ql, kh, kl, gwh, gwl, rdenom);
  k_colsum<<<dim3(kBH, 16), 256, 0, stream>>>(qh, ql, kh, kl, gwh, gwl,
                                              rdenom, alpha, rcolv);
  k_vt   <<<dim3(kBH, 16), 256, 0, stream>>>(vh, rcolv, vtg);
  k_out  <<<dim3(kBH, 8), 512, 0, stream>>>(qh, ql, kh, kl, vtg, gwh, gwl,
                                            rdenom, alpha, ctxh, ctxl);
  k_split<<<576, 256, 0, stream>>>(Wproj, Wph, Wpl);
  k_proj <<<dim3(6, 32), 512, 0, stream>>>(ctxh, ctxl, Wph, Wpl, bproj, out);
}

// Round 9
// 253.682 us; speedup vs baseline: 1.3723x; 1.0952x over previous
//
#include <hip/hip_runtime.h>
#include <math.h>

namespace {

constexpr int kN   = 1024;
constexpr int kDim = 768;
constexpr int kH   = 12;
constexpr int kBH  = 48;
constexpr float kScale = 0.125f;  // HD^-0.5 (folded into q at k_qkv)

typedef __attribute__((ext_vector_type(8))) short short8;
typedef __attribute__((ext_vector_type(4))) short short4v;
typedef __attribute__((ext_vector_type(4))) float f32x4;
typedef __attribute__((ext_vector_type(16))) float f32x16;
typedef __attribute__((ext_vector_type(4))) uint uint4v;

#define MFMA(a, b, c)   __builtin_amdgcn_mfma_f32_16x16x32_bf16(a, b, c, 0, 0, 0)
#define MFMA32(a, b, c) __builtin_amdgcn_mfma_f32_32x32x16_bf16(a, b, c, 0, 0, 0)

// ---------- bf16 helpers (round-to-nearest-even) ----------
__device__ __forceinline__ ushort f2bf(float f) {
  uint u = __builtin_bit_cast(uint, f);
  u += 0x7fffu + ((u >> 16) & 1u);
  return (ushort)(u >> 16);
}
__device__ __forceinline__ float bf2f(ushort h) {
  uint u = ((uint)h) << 16;
  return __builtin_bit_cast(float, u);
}
__device__ __forceinline__ void split8(const float* f, short8& hi, short8& lo) {
  #pragma unroll
  for (int i = 0; i < 8; i++) {
    const ushort h = f2bf(f[i]);
    hi[i] = (short)h;
    lo[i] = (short)f2bf(f[i] - bf2f(h));
  }
}
__device__ __forceinline__ uint packbf(float a, float b) {
  return (uint)f2bf(a) | ((uint)f2bf(b) << 16);
}

// ---------- async global->LDS, 16B per lane ----------
__device__ __forceinline__ void gl16(const short* g, short* l) {
  __builtin_amdgcn_global_load_lds(
      (const __attribute__((address_space(1))) void*)g,
      (__attribute__((address_space(3))) void*)l, 16, 0, 0);
}

// swizzled tile: LDS[row][slot] (64 cols = 8 slots), slot = chunk ^ (row&7)
__device__ __forceinline__ short8 frag(const short* t, int row, int chunk) {
  return *(const short8*)(t + row * 64 + ((chunk ^ (row & 7)) << 3));
}

// stage ROWS x 64 bf16 tile via global_load_lds (pre-swizzled global source)
template<int ROWS, int W>
__device__ __forceinline__ void stage_tile(short* dst, const short* src,
                                           int stride, int w, int l) {
  #pragma unroll
  for (int c = 0; c < ROWS / 8; c += W) {
    const int cc = c + w;
    const int row0 = cc << 3;
    const int row = row0 + (l >> 3);
    const int ch = (l & 7) ^ (row & 7);
    gl16(src + (size_t)row * stride + (ch << 3), dst + row0 * 64);
  }
}

// ---------------- K0: fp32 -> bf16 hi/lo split -------------------------------
__global__ __launch_bounds__(256) void k_split(const float* __restrict__ src,
                                               short* __restrict__ h,
                                               short* __restrict__ l) {
  const size_t i = ((size_t)blockIdx.x * 256 + threadIdx.x) * 4;
  const float4 f = *(const float4*)(src + i);
  const float ff[4] = {f.x, f.y, f.z, f.w};
  short4v hv, lv;
  #pragma unroll
  for (int j = 0; j < 4; j++) {
    const ushort u = f2bf(ff[j]);
    hv[j] = (short)u;
    lv[j] = (short)f2bf(ff[j] - bf2f(u));
  }
  *(short4v*)(h + i) = hv;
  *(short4v*)(l + i) = lv;
}

// ---------------- K1: qkv = x @ W_qkv^T (+bias), bf16x3 MFMA, 2-phase -------
__global__ __launch_bounds__(512) void k_qkv(const short* __restrict__ xh,
                                             const short* __restrict__ xl,
                                             const short* __restrict__ wh,
                                             const short* __restrict__ wl,
                                             const float* __restrict__ bias,
                                             short* __restrict__ qh, short* __restrict__ ql,
                                             short* __restrict__ kh, short* __restrict__ kl,
                                             short* __restrict__ vh, short* __restrict__ vl) {
  __shared__ __align__(16) short sb[2][32768];
  const int bx = blockIdx.x, by = blockIdx.y;
  const int tid = threadIdx.x, w = tid >> 6, lane = tid & 63;
  const int wr = w >> 2, wc = w & 3;
  const short* Asrc_h = xh + (size_t)(by * 128) * kDim;
  const short* Asrc_l = xl + (size_t)(by * 128) * kDim;
  const short* Bsrc_h = wh + (size_t)(bx * 128) * kDim;
  const short* Bsrc_l = wl + (size_t)(bx * 128) * kDim;

  f32x4 acc[4][2] = {};
  {
    short* nb = sb[0];
    stage_tile<128, 8>(nb,          Asrc_h, kDim, w, lane);
    stage_tile<128, 8>(nb + 8192,   Asrc_l, kDim, w, lane);
    stage_tile<128, 8>(nb + 16384,  Bsrc_h, kDim, w, lane);
    stage_tile<128, 8>(nb + 24576,  Bsrc_l, kDim, w, lane);
  }
  int p = 0;
  #pragma unroll 1
  for (int t = 0; t < 12; ++t) {
    __syncthreads();
    if (t < 11) {
      const int k0 = (t + 1) * 64;
      short* nb = sb[p ^ 1];
      stage_tile<128, 8>(nb,         Asrc_h + k0, kDim, w, lane);
      stage_tile<128, 8>(nb + 8192,  Asrc_l + k0, kDim, w, lane);
      stage_tile<128, 8>(nb + 16384, Bsrc_h + k0, kDim, w, lane);
      stage_tile<128, 8>(nb + 24576, Bsrc_l + k0, kDim, w, lane);
    }
    const short* cb = sb[p];
    #pragma unroll
    for (int s = 0; s < 2; ++s) {
      const int ch = (s << 2) + (lane >> 4);
      short8 af[4], alf[4], bf_[2], blf[2];
      #pragma unroll
      for (int i = 0; i < 4; i++) {
        const int ar = wr * 64 + i * 16 + (lane & 15);
        af[i]  = frag(cb, ar, ch);
        alf[i] = frag(cb + 8192, ar, ch);
      }
      #pragma unroll
      for (int j = 0; j < 2; j++) {
        const int br = wc * 32 + j * 16 + (lane & 15);
        bf_[j] = frag(cb + 16384, br, ch);
        blf[j] = frag(cb + 24576, br, ch);
      }
      #pragma unroll
      for (int i = 0; i < 4; i++)
        #pragma unroll
        for (int j = 0; j < 2; j++) {
          acc[i][j] = MFMA(af[i], bf_[j], acc[i][j]);
          acc[i][j] = MFMA(af[i], blf[j], acc[i][j]);
          acc[i][j] = MFMA(alf[i], bf_[j], acc[i][j]);
        }
    }
    p ^= 1;
  }
  #pragma unroll
  for (int j = 0; j < 2; j++) {
    const int col = bx * 128 + wc * 32 + j * 16 + (lane & 15);
    const int part = col / 768;
    const int rem = col - part * 768;
    const int hh = rem >> 6, d = rem & 63;
    short* dh = (part == 0) ? qh : ((part == 1) ? kh : vh);
    short* dl = (part == 0) ? ql : ((part == 1) ? kl : vl);
    const float bv = bias[col];
    const float scl = (part == 0) ? kScale : 1.0f;
    #pragma unroll
    for (int i = 0; i < 4; i++) {
      #pragma unroll
      for (int r = 0; r < 4; r++) {
        const int gr = by * 128 + wr * 64 + i * 16 + ((lane >> 4) << 2) + r;
        const int b = gr >> 10, n = gr & 1023;
        const float val = (acc[i][j][r] + bv) * scl;
        const ushort hu = f2bf(val);
        const size_t idx = (size_t)((b * kH + hh) * kN + n) * 64 + d;
        dh[idx] = (short)hu;
        dl[idx] = (short)f2bf(val - bf2f(hu));
      }
    }
  }
}

// ---------------- K2: gw = softmax(gelu(v @ gp^T)) via MFMA x3 --------------
__global__ __launch_bounds__(512) void k_gw(const short* __restrict__ vh,
                                            const short* __restrict__ vl,
                                            const float* __restrict__ Wgp,
                                            short* __restrict__ gwh,
                                            short* __restrict__ gwl) {
  const int bh = blockIdx.x;
  const int h = bh % kH;
  const int n0 = blockIdx.y << 7;
  const int tid = threadIdx.x, w = tid >> 6, lane = tid & 63;
  __shared__ __align__(16) short gph[4096], gpl[4096];
  {
    const int r = tid >> 3, c = tid & 7;
    float f[8] __attribute__((aligned(16)));
    *(float4*)(f + 0) = *(const float4*)(Wgp + h * 4096 + r * 64 + c * 8);
    *(float4*)(f + 4) = *(const float4*)(Wgp + h * 4096 + r * 64 + c * 8 + 4);
    short8 hh, ll;
    split8(f, hh, ll);
    const int slot = c ^ (r & 7);
    *(short8*)(gph + r * 64 + slot * 8) = hh;
    *(short8*)(gpl + r * 64 + slot * 8) = ll;
  }
  short8 vhf[2], vlf[2];
  const size_t arow = (size_t)(bh * kN + n0 + w * 16 + (lane & 15)) * 64 + ((lane >> 4) << 3);
  vhf[0] = *(const short8*)(vh + arow); vhf[1] = *(const short8*)(vh + arow + 32);
  vlf[0] = *(const short8*)(vl + arow); vlf[1] = *(const short8*)(vl + arow + 32);
  __syncthreads();

  f32x4 aU[4] = {};
  #pragma unroll
  for (int msub = 0; msub < 4; msub++) {
    #pragma unroll
    for (int s = 0; s < 2; s++) {
      const int row = (msub << 4) + (lane & 15);
      const int ch = (s << 2) + (lane >> 4);
      const short8 bh_ = frag(gph, row, ch);
      const short8 bl_ = frag(gpl, row, ch);
      aU[msub] = MFMA(vhf[s], bh_, aU[msub]);
      aU[msub] = MFMA(vhf[s], bl_, aU[msub]);
      aU[msub] = MFMA(vlf[s], bh_, aU[msub]);
    }
  }
  #pragma unroll
  for (int r = 0; r < 4; r++) {
    float u[4];
    #pragma unroll
    for (int m = 0; m < 4; m++) {
      const float a = aU[m][r];
      u[m] = 0.5f * a * (1.0f + erff(a * 0.70710678118654752f));
    }
    float mx = fmaxf(fmaxf(u[0], u[1]), fmaxf(u[2], u[3]));
    #pragma unroll
    for (int msk = 1; msk < 16; msk <<= 1) mx = fmaxf(mx, __shfl_xor(mx, msk));
    float e[4], ssum = 0.f;
    #pragma unroll
    for (int m = 0; m < 4; m++) { e[m] = __expf(u[m] - mx); ssum += e[m]; }
    #pragma unroll
    for (int msk = 1; msk < 16; msk <<= 1) ssum += __shfl_xor(ssum, msk);
    const float inv = 1.0f / ssum;
    const int n = n0 + w * 16 + ((lane >> 4) << 2) + r;
    #pragma unroll
    for (int m = 0; m < 4; m++) {
      const float g = e[m] * inv;
      const ushort hu = f2bf(g);
      const size_t idx = (size_t)(bh * kN + n) * 64 + (m << 4) + (lane & 15);
      gwh[idx] = (short)hu;
      gwl[idx] = (short)f2bf(g - bf2f(hu));
    }
  }
}

// -------- K2b: vtg[bh][d][m] = bf16( rcol[m] * V[m][d] )  (transposed) ------
__global__ __launch_bounds__(256) void k_vt(const short* __restrict__ vh,
                                            const float* __restrict__ rcolv,
                                            short* __restrict__ vtg) {
  const int bh = blockIdx.x;
  const int n0 = blockIdx.y << 6;
  __shared__ short t[64][80];
  const int tid = threadIdx.x;
  {
    const int n = tid >> 2, d0 = (tid & 3) << 4;
    const float rc = rcolv[bh * kN + n0 + n];
    const short8 a = *(const short8*)(vh + (size_t)(bh * kN + n0 + n) * 64 + d0);
    const short8 b = *(const short8*)(vh + (size_t)(bh * kN + n0 + n) * 64 + d0 + 8);
    #pragma unroll
    for (int i = 0; i < 8; ++i) {
      t[d0 + i][n]     = (short)f2bf(bf2f((ushort)a[i]) * rc);
      t[d0 + 8 + i][n] = (short)f2bf(bf2f((ushort)b[i]) * rc);
    }
  }
  __syncthreads();
  const int d = tid >> 2, j0 = (tid & 3) << 4;
  short* dst = vtg + (size_t)bh * 65536 + (size_t)d * 1024 + n0 + j0;
  *(short8*)(dst)     = *(const short8*)(&t[d][j0]);
  *(short8*)(dst + 8) = *(const short8*)(&t[d][j0 + 8]);
}

// ------- K3: rdenom — 64 n-rows, 4 waves (2 n-grp x 2 m-half), 32KB LDS -----
// Combined 64-row tiles: rows [0:32)=m-half0 subtile, [32:64)=half1.
__global__ __launch_bounds__(256, 3) void k_denom(const short* __restrict__ qh,
                                                  const short* __restrict__ ql,
                                                  const short* __restrict__ kh,
                                                  const short* __restrict__ kl,
                                                  const short* __restrict__ gwh,
                                                  const short* __restrict__ gwl,
                                                  float* __restrict__ rdenom) {
  const int bh = blockIdx.x;
  const int n0 = blockIdx.y << 6;
  const int tid = threadIdx.x, w = tid >> 6, lane = tid & 63;
  const int lc = lane & 31, hl = lane >> 5;
  const int nw = w & 1, mh = w >> 1;
  __shared__ __align__(16) short sb[16384];  // 4 arrays x [64][64]
  __shared__ float part[4][32];

  short8 qB[4], qlB[4], gB[4], glB[4];
  {
    const size_t nrow = (size_t)(bh * kN + n0 + nw * 32 + lc) * 64;
    #pragma unroll
    for (int ks = 0; ks < 4; ks++) {
      const int off = ks * 16 + (hl << 3);
      qB[ks]  = *(const short8*)(qh  + nrow + off);
      qlB[ks] = *(const short8*)(ql  + nrow + off);
      gB[ks]  = *(const short8*)(gwh + nrow + off);
      glB[ks] = *(const short8*)(gwl + nrow + off);
    }
  }
  float dsum = 0.f;
  #pragma unroll 1
  for (int t = 0; t < 16; ++t) {
    __syncthreads();
    const size_t mo0 = (size_t)(bh * kN + t * 32) * 64;
    const size_t mo1 = (size_t)(bh * kN + 512 + t * 32) * 64;
    stage_tile<32, 4>(sb,                kh  + mo0, 64, w, lane);
    stage_tile<32, 4>(sb + 2048,         kh  + mo1, 64, w, lane);
    stage_tile<32, 4>(sb + 4096,         kl  + mo0, 64, w, lane);
    stage_tile<32, 4>(sb + 4096 + 2048,  kl  + mo1, 64, w, lane);
    stage_tile<32, 4>(sb + 8192,         gwh + mo0, 64, w, lane);
    stage_tile<32, 4>(sb + 8192 + 2048,  gwh + mo1, 64, w, lane);
    stage_tile<32, 4>(sb + 12288,        gwl + mo0, 64, w, lane);
    stage_tile<32, 4>(sb + 12288 + 2048, gwl + mo1, 64, w, lane);
    __syncthreads();
    f32x16 aS = {}, aG = {};
    #pragma unroll
    for (int ks = 0; ks < 4; ++ks) {
      const int row = mh * 32 + lc;
      const int ck = ks * 2 + hl;
      const short8 Ah_ = frag(sb, row, ck);
      const short8 Al_ = frag(sb + 4096, row, ck);
      const short8 Eh_ = frag(sb + 8192, row, ck);
      const short8 El_ = frag(sb + 12288, row, ck);
      aS = MFMA32(Ah_, qB[ks], aS);
      aS = MFMA32(Al_, qB[ks], aS);
      aS = MFMA32(Ah_, qlB[ks], aS);
      aG = MFMA32(Eh_, gB[ks], aG);
      aG = MFMA32(El_, gB[ks], aG);
      aG = MFMA32(Eh_, glB[ks], aG);
    }
    #pragma unroll
    for (int r = 0; r < 16; ++r)
      dsum += __expf(aS[r] * aG[r]);
  }
  dsum += __shfl_xor(dsum, 32);
  if (hl == 0) part[w][lc] = dsum;
  __syncthreads();
  if (tid < 64)
    rdenom[bh * kN + n0 + tid] =
        1.0f / (part[tid >> 5][tid & 31] + part[2 + (tid >> 5)][tid & 31]);
}

// ------- K4: rcol — 64 m-rows, 4 waves (2 m-grp x 2 n-half), 32KB LDS -------
__global__ __launch_bounds__(256, 3) void k_colsum(const short* __restrict__ qh,
                                                   const short* __restrict__ ql,
                                                   const short* __restrict__ kh,
                                                   const short* __restrict__ kl,
                                                   const short* __restrict__ gwh,
                                                   const short* __restrict__ gwl,
                                                   const float* __restrict__ rdenom,
                                                   const float* __restrict__ alpha,
                                                   float* __restrict__ rcolv) {
  const int bh = blockIdx.x;
  const int m0 = blockIdx.y << 6;
  const int tid = threadIdx.x, w = tid >> 6, lane = tid & 63;
  const int lc = lane & 31, hl = lane >> 5;
  const int mw = w & 1, nh = w >> 1;
  __shared__ __align__(16) short sb[16384];
  __shared__ float part[4][32];
  __shared__ float rdl[2][32];
  const float ah_ = 1.0f / (1.0f + __expf(-alpha[bh % kH]));
  const float om = 1.0f - ah_;

  short8 kB[4], klB[4], gB[4], glB[4];
  {
    const size_t mrow = (size_t)(bh * kN + m0 + mw * 32 + lc) * 64;
    #pragma unroll
    for (int ks = 0; ks < 4; ks++) {
      const int off = ks * 16 + (hl << 3);
      kB[ks]  = *(const short8*)(kh  + mrow + off);
      klB[ks] = *(const short8*)(kl  + mrow + off);
      gB[ks]  = *(const short8*)(gwh + mrow + off);
      glB[ks] = *(const short8*)(gwl + mrow + off);
    }
  }
  float csum = 0.f;
  #pragma unroll 1
  for (int t = 0; t < 16; ++t) {
    __syncthreads();
    const size_t no0 = (size_t)(bh * kN + t * 32) * 64;
    const size_t no1 = (size_t)(bh * kN + 512 + t * 32) * 64;
    stage_tile<32, 4>(sb,                qh  + no0, 64, w, lane);
    stage_tile<32, 4>(sb + 2048,         qh  + no1, 64, w, lane);
    stage_tile<32, 4>(sb + 4096,         ql  + no0, 64, w, lane);
    stage_tile<32, 4>(sb + 4096 + 2048,  ql  + no1, 64, w, lane);
    stage_tile<32, 4>(sb + 8192,         gwh + no0, 64, w, lane);
    stage_tile<32, 4>(sb + 8192 + 2048,  gwh + no1, 64, w, lane);
    stage_tile<32, 4>(sb + 12288,        gwl + no0, 64, w, lane);
    stage_tile<32, 4>(sb + 12288 + 2048, gwl + no1, 64, w, lane);
    if (tid < 64)
      rdl[tid >> 5][tid & 31] =
          rdenom[bh * kN + (tid >> 5) * 512 + t * 32 + (tid & 31)];
    __syncthreads();
    f32x16 aS = {}, aG = {};
    #pragma unroll
    for (int ks = 0; ks < 4; ++ks) {
      const int row = nh * 32 + lc;
      const int ck = ks * 2 + hl;
      const short8 Ah_ = frag(sb, row, ck);
      const short8 Al_ = frag(sb + 4096, row, ck);
      const short8 Eh_ = frag(sb + 8192, row, ck);
      const short8 El_ = frag(sb + 12288, row, ck);
      aS = MFMA32(Ah_, kB[ks], aS);
      aS = MFMA32(Al_, kB[ks], aS);
      aS = MFMA32(Ah_, klB[ks], aS);
      aG = MFMA32(Eh_, gB[ks], aG);
      aG = MFMA32(El_, gB[ks], aG);
      aG = MFMA32(Eh_, glB[ks], aG);
    }
    #pragma unroll
    for (int r = 0; r < 16; ++r) {
      const int nr = (r & 3) + ((r >> 2) << 3) + (hl << 2);
      const float g = aG[r];
      csum += om * (__expf(aS[r] * g) * rdl[nh][nr]) + ah_ * g;
    }
  }
  csum += __shfl_xor(csum, 32);
  if (hl == 0) part[w][lc] = csum;
  __syncthreads();
  if (tid < 64)
    rcolv[bh * kN + m0 + tid] =
        1.0f / (part[tid >> 5][tid & 31] + part[2 + (tid >> 5)][tid & 31] + 1e-8f);
}

// ------- K5: ctx — 64 n-rows, 4 waves (2 n-grp x 2 m-half), 40KB LDS --------
__global__ __launch_bounds__(256, 3) void k_out(const short* __restrict__ qh,
                                                const short* __restrict__ ql,
                                                const short* __restrict__ kh,
                                                const short* __restrict__ kl,
                                                const short* __restrict__ vtg,
                                                const short* __restrict__ gwh,
                                                const short* __restrict__ gwl,
                                                const float* __restrict__ rdenom,
                                                const float* __restrict__ alpha,
                                                short* __restrict__ ctxh,
                                                short* __restrict__ ctxl) {
  const int bh = blockIdx.x;
  const int h = bh % kH;
  const int b = bh / kH;
  const int n0 = blockIdx.y << 6;
  const int tid = threadIdx.x, w = tid >> 6, lane = tid & 63;
  const int lc = lane & 31, hl = lane >> 5;
  const int nw = w & 1, mh = w >> 1;
  __shared__ __align__(16) short sb[20480];  // 5 arrays x [64][64] = 40KB
  const float ah_ = 1.0f / (1.0f + __expf(-alpha[h]));
  const float om = 1.0f - ah_;

  short8 qB[4], qlB[4], gB[4], glB[4];
  {
    const size_t nrow = (size_t)(bh * kN + n0 + nw * 32 + lc) * 64;
    #pragma unroll
    for (int ks = 0; ks < 4; ks++) {
      const int off = ks * 16 + (hl << 3);
      qB[ks]  = *(const short8*)(qh  + nrow + off);
      qlB[ks] = *(const short8*)(ql  + nrow + off);
      gB[ks]  = *(const short8*)(gwh + nrow + off);
      glB[ks] = *(const short8*)(gwl + nrow + off);
    }
  }
  const float rdn = rdenom[bh * kN + n0 + nw * 32 + lc];
  const short* vbh = vtg + (size_t)bh * 65536;
  f32x16 oac[2] = {};

  #pragma unroll 1
  for (int t = 0; t < 16; ++t) {
    __syncthreads();
    const size_t mo0 = (size_t)(bh * kN + t * 32) * 64;
    const size_t mo1 = (size_t)(bh * kN + 512 + t * 32) * 64;
    stage_tile<32, 4>(sb,                kh  + mo0, 64, w, lane);
    stage_tile<32, 4>(sb + 2048,         kh  + mo1, 64, w, lane);
    stage_tile<32, 4>(sb + 4096,         kl  + mo0, 64, w, lane);
    stage_tile<32, 4>(sb + 4096 + 2048,  kl  + mo1, 64, w, lane);
    stage_tile<32, 4>(sb + 8192,         gwh + mo0, 64, w, lane);
    stage_tile<32, 4>(sb + 8192 + 2048,  gwh + mo1, 64, w, lane);
    stage_tile<32, 4>(sb + 12288,        gwl + mo0, 64, w, lane);
    stage_tile<32, 4>(sb + 12288 + 2048, gwl + mo1, 64, w, lane);
    // V' combined tile: [64 d][64 m], cols 0..31 = half0 m, 32..63 = half1
    #pragma unroll
    for (int c = 0; c < 8; c += 4) {
      const int cc = c + w;
      const int row0 = cc << 3;
      const int row = row0 + (lane >> 3);
      const int ch = (lane & 7) ^ (row & 7);
      const int mg = ((ch >> 2) ? 512 : 0) + t * 32 + ((ch & 3) << 3);
      gl16(vbh + (size_t)row * 1024 + mg, sb + 16384 + row0 * 64);
    }
    __syncthreads();
    // S/G for this wave's m-half (rows mh*32 + lc of combined tile)
    f32x16 aS = {}, aG = {};
    #pragma unroll
    for (int ks = 0; ks < 4; ++ks) {
      const int row = mh * 32 + lc;
      const int ck = ks * 2 + hl;
      const short8 Ah_ = frag(sb, row, ck);
      const short8 Al_ = frag(sb + 4096, row, ck);
      const short8 Eh_ = frag(sb + 8192, row, ck);
      const short8 El_ = frag(sb + 12288, row, ck);
      aS = MFMA32(Ah_, qB[ks], aS);
      aS = MFMA32(Al_, qB[ks], aS);
      aS = MFMA32(Ah_, qlB[ks], aS);
      aG = MFMA32(Eh_, gB[ks], aG);
      aG = MFMA32(El_, gB[ks], aG);
      aG = MFMA32(Eh_, glB[ks], aG);
    }
    float a[16];
    #pragma unroll
    for (int r = 0; r < 16; ++r) {
      const float g = aG[r];
      const float p = __expf(aS[r] * g) * rdn;
      a[r] = om * p + ah_ * g;
    }
    // pack P^T fragments (m-local 0..31, col n = lc) via cross-half shuffle
    short8 pf[2];
    {
      uint W[8], Ws[8];
      #pragma unroll
      for (int j = 0; j < 8; ++j) W[j] = packbf(a[2 * j], a[2 * j + 1]);
      #pragma unroll
      for (int j = 0; j < 8; ++j) Ws[j] = __shfl_xor(W[j], 32);
      uint4v b0, b1;
      b0[0] = hl ? Ws[2] : W[0];  b0[1] = hl ? Ws[3] : W[1];
      b0[2] = hl ? W[2]  : Ws[0]; b0[3] = hl ? W[3]  : Ws[1];
      b1[0] = hl ? Ws[6] : W[4];  b1[1] = hl ? Ws[7] : W[5];
      b1[2] = hl ? W[6]  : Ws[4]; b1[3] = hl ? W[7]  : Ws[5];
      pf[0] = __builtin_bit_cast(short8, b0);
      pf[1] = __builtin_bit_cast(short8, b1);
    }
    // PV: O^T[d,n] += V'^T[d, m-half] * P^T[m-half, n]
    #pragma unroll
    for (int dt = 0; dt < 2; ++dt)
      #pragma unroll
      for (int ks = 0; ks < 2; ++ks) {
        const short8 va = frag(sb + 16384, dt * 32 + lc, mh * 4 + ks * 2 + hl);
        oac[dt] = MFMA32(va, pf[ks], oac[dt]);
      }
  }
  // epilogue: cross-m-half add + transpose via LDS, store ctx hi/lo
  __syncthreads();
  float* buf = (float*)sb;  // [64][68] floats = 17.4KB
  if (mh == 1) {
    #pragma unroll
    for (int dt = 0; dt < 2; ++dt)
      #pragma unroll
      for (int r = 0; r < 16; ++r) {
        const int d = dt * 32 + (r & 3) + ((r >> 2) << 3) + (hl << 2);
        buf[(nw * 32 + lc) * 68 + d] = oac[dt][r];
      }
  }
  __syncthreads();
  if (mh == 0) {
    #pragma unroll
    for (int dt = 0; dt < 2; ++dt)
      #pragma unroll
      for (int r = 0; r < 16; ++r) {
        const int d = dt * 32 + (r & 3) + ((r >> 2) << 3) + (hl << 2);
        const int idx = (nw * 32 + lc) * 68 + d;
        buf[idx] = oac[dt][r] + buf[idx];
      }
  }
  __syncthreads();
  {
    const int rowi = tid >> 2;            // 0..63
    const int d0 = (tid & 3) << 4;        // 0,16,32,48
    float f[16] __attribute__((aligned(16)));
    #pragma unroll
    for (int j = 0; j < 4; ++j)
      *(float4*)(f + 4 * j) = *(const float4*)(&buf[rowi * 68 + d0 + 4 * j]);
    const int n = n0 + rowi;
    short* dsth = ctxh + (size_t)(b * kN + n) * kDim + h * 64 + d0;
    short* dstl = ctxl + (size_t)(b * kN + n) * kDim + h * 64 + d0;
    #pragma unroll
    for (int g8 = 0; g8 < 2; ++g8) {
      short8 hi, lo;
      split8(f + 8 * g8, hi, lo);
      *(short8*)(dsth + 8 * g8) = hi;
      *(short8*)(dstl + 8 * g8) = lo;
    }
  }
}

// ---------------- K6: out = ctx @ W_proj^T + b_proj, bf16x4, 2-phase --------
__global__ __launch_bounds__(512) void k_proj(const short* __restrict__ ch_,
                                              const short* __restrict__ cl_,
                                              const short* __restrict__ wh,
                                              const short* __restrict__ wl,
                                              const float* __restrict__ bias,
                                              float* __restrict__ out) {
  __shared__ __align__(16) short sb[2][32768];
  const int bx = blockIdx.x, by = blockIdx.y;
  const int tid = threadIdx.x, w = tid >> 6, lane = tid & 63;
  const int wr = w >> 2, wc = w & 3;
  const short* Asrc_h = ch_ + (size_t)(by * 128) * kDim;
  const short* Asrc_l = cl_ + (size_t)(by * 128) * kDim;
  const short* Bsrc_h = wh + (size_t)(bx * 128) * kDim;
  const short* Bsrc_l = wl + (size_t)(bx * 128) * kDim;

  f32x4 acc[4][2] = {};
  {
    short* nb = sb[0];
    stage_tile<128, 8>(nb,         Asrc_h, kDim, w, lane);
    stage_tile<128, 8>(nb + 8192,  Asrc_l, kDim, w, lane);
    stage_tile<128, 8>(nb + 16384, Bsrc_h, kDim, w, lane);
    stage_tile<128, 8>(nb + 24576, Bsrc_l, kDim, w, lane);
  }
  int p = 0;
  #pragma unroll 1
  for (int t = 0; t < 12; ++t) {
    __syncthreads();
    if (t < 11) {
      const int k0 = (t + 1) * 64;
      short* nb = sb[p ^ 1];
      stage_tile<128, 8>(nb,         Asrc_h + k0, kDim, w, lane);
      stage_tile<128, 8>(nb + 8192,  Asrc_l + k0, kDim, w, lane);
      stage_tile<128, 8>(nb + 16384, Bsrc_h + k0, kDim, w, lane);
      stage_tile<128, 8>(nb + 24576, Bsrc_l + k0, kDim, w, lane);
    }
    const short* cb = sb[p];
    #pragma unroll
    for (int s = 0; s < 2; ++s) {
      const int ch = (s << 2) + (lane >> 4);
      short8 af[4], alf[4], bf_[2], blf[2];
      #pragma unroll
      for (int i = 0; i < 4; i++) {
        const int ar = wr * 64 + i * 16 + (lane & 15);
        af[i]  = frag(cb, ar, ch);
        alf[i] = frag(cb + 8192, ar, ch);
      }
      #pragma unroll
      for (int j = 0; j < 2; j++) {
        const int br = wc * 32 + j * 16 + (lane & 15);
        bf_[j] = frag(cb + 16384, br, ch);
        blf[j] = frag(cb + 24576, br, ch);
      }
      #pragma unroll
      for (int i = 0; i < 4; i++)
        #pragma unroll
        for (int j = 0; j < 2; j++) {
          acc[i][j] = MFMA(af[i], bf_[j], acc[i][j]);
          acc[i][j] = MFMA(af[i], blf[j], acc[i][j]);
          acc[i][j] = MFMA(alf[i], bf_[j], acc[i][j]);
          acc[i][j] = MFMA(alf[i], blf[j], acc[i][j]);
        }
    }
    p ^= 1;
  }
  #pragma unroll
  for (int j = 0; j < 2; j++) {
    const int col = bx * 128 + wc * 32 + j * 16 + (lane & 15);
    const float bv = bias[col];
    #pragma unroll
    for (int i = 0; i < 4; i++) {
      #pragma unroll
      for (int r = 0; r < 4; r++) {
        const int row = by * 128 + wr * 64 + i * 16 + ((lane >> 4) << 2) + r;
        out[(size_t)row * kDim + col] = acc[i][j][r] + bv;
      }
    }
  }
}

}  // namespace

extern "C" void kernel_launch(void* const* d_in, const int* in_sizes, int n_in,
                              void* d_out, int out_size, void* d_ws, size_t ws_size,
                              hipStream_t stream) {
  const float* x     = (const float*)d_in[0];
  const float* Wqkv  = (const float*)d_in[1];
  const float* bqkv  = (const float*)d_in[2];
  const float* Wgp   = (const float*)d_in[3];
  const float* alpha = (const float*)d_in[4];
  const float* Wproj = (const float*)d_in[5];
  const float* bproj = (const float*)d_in[6];
  float* out = (float*)d_out;

  // workspace: 10 bf16 regions of 3,145,728 elems + 2 small fp32 (63.3 MB).
  // Aliases: Wq-split in gw region; vtg in vl region (vl dead after k_gw);
  //          ctx in x region; Wp-split in q region.
  const size_t he = 3145728;
  short* qh  = (short*)d_ws;
  short* ql  = qh + he;
  short* kh  = ql + he;
  short* kl  = kh + he;
  short* vh  = kl + he;
  short* vl  = vh + he;
  short* gwh = vl + he;
  short* gwl = gwh + he;
  short* xh  = gwl + he;
  short* xl  = xh + he;
  float* rdenom = (float*)(xl + he);
  float* rcolv  = rdenom + (size_t)kBH * kN;

  short* Wqh = gwh;  short* Wql = gwl;
  short* vtg = vl;           // [48][64][1024] = rcol-scaled V^T
  short* ctxh = xh;  short* ctxl = xl;
  short* Wph = qh;   short* Wpl = ql;

  k_split<<<3072, 256, 0, stream>>>(x, xh, xl);
  k_split<<<1728, 256, 0, stream>>>(Wqkv, Wqh, Wql);
  k_qkv  <<<dim3(18, 32), 512, 0, stream>>>(xh, xl, Wqh, Wql, bqkv,
                                            qh, ql, kh, kl, vh, vl);
  k_gw   <<<dim3(kBH, 8), 512, 0, stream>>>(vh, vl, Wgp, gwh, gwl);
  k_denom<<<dim3(kBH, 16), 256, 0, stream>>>(qh, ql, kh, kl, gwh, gwl, rdenom);
  k_colsum<<<dim3(kBH, 16), 256, 0, stream>>>(qh, ql, kh, kl, gwh, gwl,
                                              rdenom, alpha, rcolv);
  k_vt   <<<dim3(kBH, 16), 256, 0, stream>>>(vh, rcolv, vtg);
  k_out  <<<dim3(kBH, 16), 256, 0, stream>>>(qh, ql, kh, kl, vtg, gwh, gwl,
                                             rdenom, alpha, ctxh, ctxl);
  k_split<<<576, 256, 0, stream>>>(Wproj, Wph, Wpl);
  k_proj <<<dim3(6, 32), 512, 0, stream>>>(ctxh, ctxl, Wph, Wpl, bproj, out);
}

// Round 10
// 225.331 us; speedup vs baseline: 1.5449x; 1.1258x over previous
//
#include <hip/hip_runtime.h>
#include <math.h>

namespace {

constexpr int kN   = 1024;
constexpr int kDim = 768;
constexpr int kH   = 12;
constexpr int kBH  = 48;
constexpr float kScale = 0.125f;  // HD^-0.5 (folded into q at k_qkv)

typedef __attribute__((ext_vector_type(8))) short short8;
typedef __attribute__((ext_vector_type(4))) short short4v;
typedef __attribute__((ext_vector_type(4))) float f32x4;
typedef __attribute__((ext_vector_type(16))) float f32x16;
typedef __attribute__((ext_vector_type(4))) uint uint4v;
typedef _Float16 f16x8 __attribute__((ext_vector_type(8)));

#define MFMA(a, b, c)      __builtin_amdgcn_mfma_f32_16x16x32_bf16(a, b, c, 0, 0, 0)
#define MFMA32(a, b, c)    __builtin_amdgcn_mfma_f32_32x32x16_bf16(a, b, c, 0, 0, 0)
#define MFMA32F16(a, b, c) __builtin_amdgcn_mfma_f32_32x32x16_f16(a, b, c, 0, 0, 0)

// ---------- bf16 helpers (round-to-nearest-even) ----------
__device__ __forceinline__ ushort f2bf(float f) {
  uint u = __builtin_bit_cast(uint, f);
  u += 0x7fffu + ((u >> 16) & 1u);
  return (ushort)(u >> 16);
}
__device__ __forceinline__ float bf2f(ushort h) {
  uint u = ((uint)h) << 16;
  return __builtin_bit_cast(float, u);
}
__device__ __forceinline__ void split8(const float* f, short8& hi, short8& lo) {
  #pragma unroll
  for (int i = 0; i < 8; i++) {
    const ushort h = f2bf(f[i]);
    hi[i] = (short)h;
    lo[i] = (short)f2bf(f[i] - bf2f(h));
  }
}
__device__ __forceinline__ uint packbf(float a, float b) {
  return (uint)f2bf(a) | ((uint)f2bf(b) << 16);
}
__device__ __forceinline__ ushort f2h(float f) {
  return __builtin_bit_cast(ushort, (_Float16)f);
}

// ---------- async global->LDS, 16B per lane ----------
__device__ __forceinline__ void gl16(const void* g, void* l) {
  __builtin_amdgcn_global_load_lds(
      (const __attribute__((address_space(1))) void*)g,
      (__attribute__((address_space(3))) void*)l, 16, 0, 0);
}

// swizzled tile: LDS[row][slot] (64 cols = 8 slots), slot = chunk ^ (row&7)
__device__ __forceinline__ short8 frag(const short* t, int row, int chunk) {
  return *(const short8*)(t + row * 64 + ((chunk ^ (row & 7)) << 3));
}

// stage ROWS x 64 2B-elem tile via global_load_lds (pre-swizzled global src)
template<int ROWS, int W>
__device__ __forceinline__ void stage_tile(short* dst, const short* src,
                                           int stride, int w, int l) {
  #pragma unroll
  for (int c = 0; c < ROWS / 8; c += W) {
    const int cc = c + w;
    const int row0 = cc << 3;
    const int row = row0 + (l >> 3);
    const int ch = (l & 7) ^ (row & 7);
    gl16(src + (size_t)row * stride + (ch << 3), dst + row0 * 64);
  }
}

// ---------------- K0: fp32 -> bf16 hi/lo split -------------------------------
__global__ __launch_bounds__(256) void k_split(const float* __restrict__ src,
                                               short* __restrict__ h,
                                               short* __restrict__ l) {
  const size_t i = ((size_t)blockIdx.x * 256 + threadIdx.x) * 4;
  const float4 f = *(const float4*)(src + i);
  const float ff[4] = {f.x, f.y, f.z, f.w};
  short4v hv, lv;
  #pragma unroll
  for (int j = 0; j < 4; j++) {
    const ushort u = f2bf(ff[j]);
    hv[j] = (short)u;
    lv[j] = (short)f2bf(ff[j] - bf2f(u));
  }
  *(short4v*)(h + i) = hv;
  *(short4v*)(l + i) = lv;
}

// ---------------- K1: qkv = x @ W_qkv^T (+bias), bf16x3 MFMA, 2-phase -------
__global__ __launch_bounds__(512) void k_qkv(const short* __restrict__ xh,
                                             const short* __restrict__ xl,
                                             const short* __restrict__ wh,
                                             const short* __restrict__ wl,
                                             const float* __restrict__ bias,
                                             short* __restrict__ qh, short* __restrict__ ql,
                                             short* __restrict__ kh, short* __restrict__ kl,
                                             short* __restrict__ vh, short* __restrict__ vl) {
  __shared__ __align__(16) short sb[2][32768];
  const int bx = blockIdx.x, by = blockIdx.y;
  const int tid = threadIdx.x, w = tid >> 6, lane = tid & 63;
  const int wr = w >> 2, wc = w & 3;
  const short* Asrc_h = xh + (size_t)(by * 128) * kDim;
  const short* Asrc_l = xl + (size_t)(by * 128) * kDim;
  const short* Bsrc_h = wh + (size_t)(bx * 128) * kDim;
  const short* Bsrc_l = wl + (size_t)(bx * 128) * kDim;

  f32x4 acc[4][2] = {};
  {
    short* nb = sb[0];
    stage_tile<128, 8>(nb,          Asrc_h, kDim, w, lane);
    stage_tile<128, 8>(nb + 8192,   Asrc_l, kDim, w, lane);
    stage_tile<128, 8>(nb + 16384,  Bsrc_h, kDim, w, lane);
    stage_tile<128, 8>(nb + 24576,  Bsrc_l, kDim, w, lane);
  }
  int p = 0;
  #pragma unroll 1
  for (int t = 0; t < 12; ++t) {
    __syncthreads();
    if (t < 11) {
      const int k0 = (t + 1) * 64;
      short* nb = sb[p ^ 1];
      stage_tile<128, 8>(nb,         Asrc_h + k0, kDim, w, lane);
      stage_tile<128, 8>(nb + 8192,  Asrc_l + k0, kDim, w, lane);
      stage_tile<128, 8>(nb + 16384, Bsrc_h + k0, kDim, w, lane);
      stage_tile<128, 8>(nb + 24576, Bsrc_l + k0, kDim, w, lane);
    }
    const short* cb = sb[p];
    #pragma unroll
    for (int s = 0; s < 2; ++s) {
      const int ch = (s << 2) + (lane >> 4);
      short8 af[4], alf[4], bf_[2], blf[2];
      #pragma unroll
      for (int i = 0; i < 4; i++) {
        const int ar = wr * 64 + i * 16 + (lane & 15);
        af[i]  = frag(cb, ar, ch);
        alf[i] = frag(cb + 8192, ar, ch);
      }
      #pragma unroll
      for (int j = 0; j < 2; j++) {
        const int br = wc * 32 + j * 16 + (lane & 15);
        bf_[j] = frag(cb + 16384, br, ch);
        blf[j] = frag(cb + 24576, br, ch);
      }
      #pragma unroll
      for (int i = 0; i < 4; i++)
        #pragma unroll
        for (int j = 0; j < 2; j++) {
          acc[i][j] = MFMA(af[i], bf_[j], acc[i][j]);
          acc[i][j] = MFMA(af[i], blf[j], acc[i][j]);
          acc[i][j] = MFMA(alf[i], bf_[j], acc[i][j]);
        }
    }
    p ^= 1;
  }
  #pragma unroll
  for (int j = 0; j < 2; j++) {
    const int col = bx * 128 + wc * 32 + j * 16 + (lane & 15);
    const int part = col / 768;
    const int rem = col - part * 768;
    const int hh = rem >> 6, d = rem & 63;
    short* dh = (part == 0) ? qh : ((part == 1) ? kh : vh);
    short* dl = (part == 0) ? ql : ((part == 1) ? kl : vl);
    const float bv = bias[col];
    const float scl = (part == 0) ? kScale : 1.0f;
    #pragma unroll
    for (int i = 0; i < 4; i++) {
      #pragma unroll
      for (int r = 0; r < 4; r++) {
        const int gr = by * 128 + wr * 64 + i * 16 + ((lane >> 4) << 2) + r;
        const int b = gr >> 10, n = gr & 1023;
        const float val = (acc[i][j][r] + bv) * scl;
        const ushort hu = f2bf(val);
        const size_t idx = (size_t)((b * kH + hh) * kN + n) * 64 + d;
        dh[idx] = (short)hu;
        dl[idx] = (short)f2bf(val - bf2f(hu));
      }
    }
  }
}

// ---------------- K2: gw = softmax(gelu(v @ gp^T)) via MFMA x3 --------------
__global__ __launch_bounds__(512) void k_gw(const short* __restrict__ vh,
                                            const short* __restrict__ vl,
                                            const float* __restrict__ Wgp,
                                            short* __restrict__ gwh,
                                            short* __restrict__ gwl) {
  const int bh = blockIdx.x;
  const int h = bh % kH;
  const int n0 = blockIdx.y << 7;
  const int tid = threadIdx.x, w = tid >> 6, lane = tid & 63;
  __shared__ __align__(16) short gph[4096], gpl[4096];
  {
    const int r = tid >> 3, c = tid & 7;
    float f[8] __attribute__((aligned(16)));
    *(float4*)(f + 0) = *(const float4*)(Wgp + h * 4096 + r * 64 + c * 8);
    *(float4*)(f + 4) = *(const float4*)(Wgp + h * 4096 + r * 64 + c * 8 + 4);
    short8 hh, ll;
    split8(f, hh, ll);
    const int slot = c ^ (r & 7);
    *(short8*)(gph + r * 64 + slot * 8) = hh;
    *(short8*)(gpl + r * 64 + slot * 8) = ll;
  }
  short8 vhf[2], vlf[2];
  const size_t arow = (size_t)(bh * kN + n0 + w * 16 + (lane & 15)) * 64 + ((lane >> 4) << 3);
  vhf[0] = *(const short8*)(vh + arow); vhf[1] = *(const short8*)(vh + arow + 32);
  vlf[0] = *(const short8*)(vl + arow); vlf[1] = *(const short8*)(vl + arow + 32);
  __syncthreads();

  f32x4 aU[4] = {};
  #pragma unroll
  for (int msub = 0; msub < 4; msub++) {
    #pragma unroll
    for (int s = 0; s < 2; s++) {
      const int row = (msub << 4) + (lane & 15);
      const int ch = (s << 2) + (lane >> 4);
      const short8 bh_ = frag(gph, row, ch);
      const short8 bl_ = frag(gpl, row, ch);
      aU[msub] = MFMA(vhf[s], bh_, aU[msub]);
      aU[msub] = MFMA(vhf[s], bl_, aU[msub]);
      aU[msub] = MFMA(vlf[s], bh_, aU[msub]);
    }
  }
  #pragma unroll
  for (int r = 0; r < 4; r++) {
    float u[4];
    #pragma unroll
    for (int m = 0; m < 4; m++) {
      const float a = aU[m][r];
      u[m] = 0.5f * a * (1.0f + erff(a * 0.70710678118654752f));
    }
    float mx = fmaxf(fmaxf(u[0], u[1]), fmaxf(u[2], u[3]));
    #pragma unroll
    for (int msk = 1; msk < 16; msk <<= 1) mx = fmaxf(mx, __shfl_xor(mx, msk));
    float e[4], ssum = 0.f;
    #pragma unroll
    for (int m = 0; m < 4; m++) { e[m] = __expf(u[m] - mx); ssum += e[m]; }
    #pragma unroll
    for (int msk = 1; msk < 16; msk <<= 1) ssum += __shfl_xor(ssum, msk);
    const float inv = 1.0f / ssum;
    const int n = n0 + w * 16 + ((lane >> 4) << 2) + r;
    #pragma unroll
    for (int m = 0; m < 4; m++) {
      const float g = e[m] * inv;
      const ushort hu = f2bf(g);
      const size_t idx = (size_t)(bh * kN + n) * 64 + (m << 4) + (lane & 15);
      gwh[idx] = (short)hu;
      gwl[idx] = (short)f2bf(g - bf2f(hu));
    }
  }
}

// -------- K2b: vt[bh][d][m] = rcol[m] * V[m][d]  (transposed; F16 or bf16) --
template<int F16>
__global__ __launch_bounds__(256) void k_vt(const short* __restrict__ vh,
                                            const float* __restrict__ rcolv,
                                            short* __restrict__ vtg) {
  const int bh = blockIdx.x;
  const int n0 = blockIdx.y << 6;
  __shared__ short t[64][80];
  const int tid = threadIdx.x;
  {
    const int n = tid >> 2, d0 = (tid & 3) << 4;
    const float rc = rcolv[bh * kN + n0 + n];
    const short8 a = *(const short8*)(vh + (size_t)(bh * kN + n0 + n) * 64 + d0);
    const short8 b = *(const short8*)(vh + (size_t)(bh * kN + n0 + n) * 64 + d0 + 8);
    #pragma unroll
    for (int i = 0; i < 8; ++i) {
      const float v0 = bf2f((ushort)a[i]) * rc;
      const float v1 = bf2f((ushort)b[i]) * rc;
      t[d0 + i][n]     = F16 ? (short)f2h(v0) : (short)f2bf(v0);
      t[d0 + 8 + i][n] = F16 ? (short)f2h(v1) : (short)f2bf(v1);
    }
  }
  __syncthreads();
  const int d = tid >> 2, j0 = (tid & 3) << 4;
  short* dst = vtg + (size_t)bh * 65536 + (size_t)d * 1024 + n0 + j0;
  *(short8*)(dst)     = *(const short8*)(&t[d][j0]);
  *(short8*)(dst + 8) = *(const short8*)(&t[d][j0 + 8]);
}

// ------- K3: rdenom — 64 n-rows, 4 waves (2 n-grp x 2 m-half), 32KB LDS -----
__global__ __launch_bounds__(256, 3) void k_denom(const short* __restrict__ qh,
                                                  const short* __restrict__ ql,
                                                  const short* __restrict__ kh,
                                                  const short* __restrict__ kl,
                                                  const short* __restrict__ gwh,
                                                  const short* __restrict__ gwl,
                                                  float* __restrict__ rdenom) {
  const int bh = blockIdx.x;
  const int n0 = blockIdx.y << 6;
  const int tid = threadIdx.x, w = tid >> 6, lane = tid & 63;
  const int lc = lane & 31, hl = lane >> 5;
  const int nw = w & 1, mh = w >> 1;
  __shared__ __align__(16) short sb[16384];
  __shared__ float part[4][32];

  short8 qB[4], qlB[4], gB[4], glB[4];
  {
    const size_t nrow = (size_t)(bh * kN + n0 + nw * 32 + lc) * 64;
    #pragma unroll
    for (int ks = 0; ks < 4; ks++) {
      const int off = ks * 16 + (hl << 3);
      qB[ks]  = *(const short8*)(qh  + nrow + off);
      qlB[ks] = *(const short8*)(ql  + nrow + off);
      gB[ks]  = *(const short8*)(gwh + nrow + off);
      glB[ks] = *(const short8*)(gwl + nrow + off);
    }
  }
  float dsum = 0.f;
  #pragma unroll 1
  for (int t = 0; t < 16; ++t) {
    __syncthreads();
    const size_t mo0 = (size_t)(bh * kN + t * 32) * 64;
    const size_t mo1 = (size_t)(bh * kN + 512 + t * 32) * 64;
    stage_tile<32, 4>(sb,                kh  + mo0, 64, w, lane);
    stage_tile<32, 4>(sb + 2048,         kh  + mo1, 64, w, lane);
    stage_tile<32, 4>(sb + 4096,         kl  + mo0, 64, w, lane);
    stage_tile<32, 4>(sb + 4096 + 2048,  kl  + mo1, 64, w, lane);
    stage_tile<32, 4>(sb + 8192,         gwh + mo0, 64, w, lane);
    stage_tile<32, 4>(sb + 8192 + 2048,  gwh + mo1, 64, w, lane);
    stage_tile<32, 4>(sb + 12288,        gwl + mo0, 64, w, lane);
    stage_tile<32, 4>(sb + 12288 + 2048, gwl + mo1, 64, w, lane);
    __syncthreads();
    f32x16 aS = {}, aG = {};
    #pragma unroll
    for (int ks = 0; ks < 4; ++ks) {
      const int row = mh * 32 + lc;
      const int ck = ks * 2 + hl;
      const short8 Ah_ = frag(sb, row, ck);
      const short8 Al_ = frag(sb + 4096, row, ck);
      const short8 Eh_ = frag(sb + 8192, row, ck);
      const short8 El_ = frag(sb + 12288, row, ck);
      aS = MFMA32(Ah_, qB[ks], aS);
      aS = MFMA32(Al_, qB[ks], aS);
      aS = MFMA32(Ah_, qlB[ks], aS);
      aG = MFMA32(Eh_, gB[ks], aG);
      aG = MFMA32(El_, gB[ks], aG);
      aG = MFMA32(Eh_, glB[ks], aG);
    }
    #pragma unroll
    for (int r = 0; r < 16; ++r)
      dsum += __expf(aS[r] * aG[r]);
  }
  dsum += __shfl_xor(dsum, 32);
  if (hl == 0) part[w][lc] = dsum;
  __syncthreads();
  if (tid < 64)
    rdenom[bh * kN + n0 + tid] =
        1.0f / (part[tid >> 5][tid & 31] + part[2 + (tid >> 5)][tid & 31]);
}

// ------- K4: rcol — 64 m-rows; optionally writes A=om*p+ah*g as fp16 --------
template<int WA>
__global__ __launch_bounds__(256, 3) void k_colsum(const short* __restrict__ qh,
                                                   const short* __restrict__ ql,
                                                   const short* __restrict__ kh,
                                                   const short* __restrict__ kl,
                                                   const short* __restrict__ gwh,
                                                   const short* __restrict__ gwl,
                                                   const float* __restrict__ rdenom,
                                                   const float* __restrict__ alpha,
                                                   float* __restrict__ rcolv,
                                                   ushort* __restrict__ Ab) {
  const int bh = blockIdx.x;
  const int m0 = blockIdx.y << 6;
  const int tid = threadIdx.x, w = tid >> 6, lane = tid & 63;
  const int lc = lane & 31, hl = lane >> 5;
  const int mw = w & 1, nh = w >> 1;
  __shared__ __align__(16) short sb[16384];
  __shared__ float part[4][32];
  __shared__ float rdl[2][32];
  const float ah_ = 1.0f / (1.0f + __expf(-alpha[bh % kH]));
  const float om = 1.0f - ah_;
  const int m_g = m0 + mw * 32 + lc;
  ushort* Arow = WA ? (Ab + ((size_t)bh << 20) + m_g) : nullptr;

  short8 kB[4], klB[4], gB[4], glB[4];
  {
    const size_t mrow = (size_t)(bh * kN + m_g) * 64;
    #pragma unroll
    for (int ks = 0; ks < 4; ks++) {
      const int off = ks * 16 + (hl << 3);
      kB[ks]  = *(const short8*)(kh  + mrow + off);
      klB[ks] = *(const short8*)(kl  + mrow + off);
      gB[ks]  = *(const short8*)(gwh + mrow + off);
      glB[ks] = *(const short8*)(gwl + mrow + off);
    }
  }
  float csum = 0.f;
  #pragma unroll 1
  for (int t = 0; t < 16; ++t) {
    __syncthreads();
    const size_t no0 = (size_t)(bh * kN + t * 32) * 64;
    const size_t no1 = (size_t)(bh * kN + 512 + t * 32) * 64;
    stage_tile<32, 4>(sb,                qh  + no0, 64, w, lane);
    stage_tile<32, 4>(sb + 2048,         qh  + no1, 64, w, lane);
    stage_tile<32, 4>(sb + 4096,         ql  + no0, 64, w, lane);
    stage_tile<32, 4>(sb + 4096 + 2048,  ql  + no1, 64, w, lane);
    stage_tile<32, 4>(sb + 8192,         gwh + no0, 64, w, lane);
    stage_tile<32, 4>(sb + 8192 + 2048,  gwh + no1, 64, w, lane);
    stage_tile<32, 4>(sb + 12288,        gwl + no0, 64, w, lane);
    stage_tile<32, 4>(sb + 12288 + 2048, gwl + no1, 64, w, lane);
    if (tid < 64)
      rdl[tid >> 5][tid & 31] =
          rdenom[bh * kN + (tid >> 5) * 512 + t * 32 + (tid & 31)];
    __syncthreads();
    f32x16 aS = {}, aG = {};
    #pragma unroll
    for (int ks = 0; ks < 4; ++ks) {
      const int row = nh * 32 + lc;
      const int ck = ks * 2 + hl;
      const short8 Ah_ = frag(sb, row, ck);
      const short8 Al_ = frag(sb + 4096, row, ck);
      const short8 Eh_ = frag(sb + 8192, row, ck);
      const short8 El_ = frag(sb + 12288, row, ck);
      aS = MFMA32(Ah_, kB[ks], aS);
      aS = MFMA32(Al_, kB[ks], aS);
      aS = MFMA32(Ah_, klB[ks], aS);
      aG = MFMA32(Eh_, gB[ks], aG);
      aG = MFMA32(El_, gB[ks], aG);
      aG = MFMA32(Eh_, glB[ks], aG);
    }
    #pragma unroll
    for (int r = 0; r < 16; ++r) {
      const int nr = (r & 3) + ((r >> 2) << 3) + (hl << 2);
      const float g = aG[r];
      const float a = om * (__expf(aS[r] * g) * rdl[nh][nr]) + ah_ * g;
      csum += a;
      if (WA) {
        const int n_g = nh * 512 + t * 32 + nr;
        Arow[(size_t)n_g << 10] = f2h(a);
      }
    }
  }
  csum += __shfl_xor(csum, 32);
  if (hl == 0) part[w][lc] = csum;
  __syncthreads();
  if (tid < 64)
    rcolv[bh * kN + m0 + tid] =
        1.0f / (part[tid >> 5][tid & 31] + part[2 + (tid >> 5)][tid & 31] + 1e-8f);
}

// ------- K5a: ctx via materialized A (fp16 GEMM O^T = V'^T @ A^T) -----------
__global__ __launch_bounds__(256) void k_outA(const ushort* __restrict__ Ab,
                                              const short* __restrict__ vtf,
                                              short* __restrict__ ctxh,
                                              short* __restrict__ ctxl) {
  const int bh = blockIdx.x;
  const int h = bh % kH;
  const int b = bh / kH;
  const int n0 = blockIdx.y << 6;
  const int tid = threadIdx.x, w = tid >> 6, lane = tid & 63;
  const int lc = lane & 31, hl = lane >> 5;
  const int nw = w & 1, mh = w >> 1;
  __shared__ __align__(16) short sbm[10240];  // At 8KB | Vt 8KB; epi buf 17.4KB
  short* At = sbm;
  short* Vt = sbm + 4096;
  const ushort* Abh = Ab + ((size_t)bh << 20);
  const short* Vbh = vtf + ((size_t)bh << 16);
  f32x16 oac[2] = {};

  #pragma unroll 1
  for (int t = 0; t < 16; ++t) {
    __syncthreads();
    #pragma unroll
    for (int c = 0; c < 8; c += 4) {
      const int cc = c + w;
      const int row0 = cc << 3;
      const int row = row0 + (lane >> 3);
      const int ce = (lane & 7) ^ (row & 7);
      const int mg = ((ce >> 2) ? 512 : 0) + t * 32 + ((ce & 3) << 3);
      gl16(Abh + ((size_t)(n0 + row) << 10) + mg, At + row0 * 64);
      gl16(Vbh + ((size_t)row << 10) + mg, Vt + row0 * 64);
    }
    __syncthreads();
    #pragma unroll
    for (int dt = 0; dt < 2; ++dt)
      #pragma unroll
      for (int ks = 0; ks < 2; ++ks) {
        const int ck = mh * 4 + ks * 2 + hl;
        const f16x8 va = __builtin_bit_cast(f16x8, frag(Vt, dt * 32 + lc, ck));
        const f16x8 pe = __builtin_bit_cast(f16x8, frag(At, nw * 32 + lc, ck));
        oac[dt] = MFMA32F16(va, pe, oac[dt]);
      }
  }
  // epilogue: cross-m-half add + transpose via LDS, store ctx hi/lo
  __syncthreads();
  float* buf = (float*)sbm;  // [64][68] floats = 17.4KB
  if (mh == 1) {
    #pragma unroll
    for (int dt = 0; dt < 2; ++dt)
      #pragma unroll
      for (int r = 0; r < 16; ++r) {
        const int d = dt * 32 + (r & 3) + ((r >> 2) << 3) + (hl << 2);
        buf[(nw * 32 + lc) * 68 + d] = oac[dt][r];
      }
  }
  __syncthreads();
  if (mh == 0) {
    #pragma unroll
    for (int dt = 0; dt < 2; ++dt)
      #pragma unroll
      for (int r = 0; r < 16; ++r) {
        const int d = dt * 32 + (r & 3) + ((r >> 2) << 3) + (hl << 2);
        const int idx = (nw * 32 + lc) * 68 + d;
        buf[idx] = oac[dt][r] + buf[idx];
      }
  }
  __syncthreads();
  {
    const int rowi = tid >> 2;
    const int d0 = (tid & 3) << 4;
    float f[16] __attribute__((aligned(16)));
    #pragma unroll
    for (int j = 0; j < 4; ++j)
      *(float4*)(f + 4 * j) = *(const float4*)(&buf[rowi * 68 + d0 + 4 * j]);
    const int n = n0 + rowi;
    short* dsth = ctxh + (size_t)(b * kN + n) * kDim + h * 64 + d0;
    short* dstl = ctxl + (size_t)(b * kN + n) * kDim + h * 64 + d0;
    #pragma unroll
    for (int g8 = 0; g8 < 2; ++g8) {
      short8 hi, lo;
      split8(f + 8 * g8, hi, lo);
      *(short8*)(dsth + 8 * g8) = hi;
      *(short8*)(dstl + 8 * g8) = lo;
    }
  }
}

// ------- K5b (fallback): ctx recompute sweep (R9 version, bf16 V') ----------
__global__ __launch_bounds__(256, 3) void k_out9(const short* __restrict__ qh,
                                                 const short* __restrict__ ql,
                                                 const short* __restrict__ kh,
                                                 const short* __restrict__ kl,
                                                 const short* __restrict__ vtg,
                                                 const short* __restrict__ gwh,
                                                 const short* __restrict__ gwl,
                                                 const float* __restrict__ rdenom,
                                                 const float* __restrict__ alpha,
                                                 short* __restrict__ ctxh,
                                                 short* __restrict__ ctxl) {
  const int bh = blockIdx.x;
  const int h = bh % kH;
  const int b = bh / kH;
  const int n0 = blockIdx.y << 6;
  const int tid = threadIdx.x, w = tid >> 6, lane = tid & 63;
  const int lc = lane & 31, hl = lane >> 5;
  const int nw = w & 1, mh = w >> 1;
  __shared__ __align__(16) short sb[20480];
  const float ah_ = 1.0f / (1.0f + __expf(-alpha[h]));
  const float om = 1.0f - ah_;

  short8 qB[4], qlB[4], gB[4], glB[4];
  {
    const size_t nrow = (size_t)(bh * kN + n0 + nw * 32 + lc) * 64;
    #pragma unroll
    for (int ks = 0; ks < 4; ks++) {
      const int off = ks * 16 + (hl << 3);
      qB[ks]  = *(const short8*)(qh  + nrow + off);
      qlB[ks] = *(const short8*)(ql  + nrow + off);
      gB[ks]  = *(const short8*)(gwh + nrow + off);
      glB[ks] = *(const short8*)(gwl + nrow + off);
    }
  }
  const float rdn = rdenom[bh * kN + n0 + nw * 32 + lc];
  const short* vbh = vtg + (size_t)bh * 65536;
  f32x16 oac[2] = {};

  #pragma unroll 1
  for (int t = 0; t < 16; ++t) {
    __syncthreads();
    const size_t mo0 = (size_t)(bh * kN + t * 32) * 64;
    const size_t mo1 = (size_t)(bh * kN + 512 + t * 32) * 64;
    stage_tile<32, 4>(sb,                kh  + mo0, 64, w, lane);
    stage_tile<32, 4>(sb + 2048,         kh  + mo1, 64, w, lane);
    stage_tile<32, 4>(sb + 4096,         kl  + mo0, 64, w, lane);
    stage_tile<32, 4>(sb + 4096 + 2048,  kl  + mo1, 64, w, lane);
    stage_tile<32, 4>(sb + 8192,         gwh + mo0, 64, w, lane);
    stage_tile<32, 4>(sb + 8192 + 2048,  gwh + mo1, 64, w, lane);
    stage_tile<32, 4>(sb + 12288,        gwl + mo0, 64, w, lane);
    stage_tile<32, 4>(sb + 12288 + 2048, gwl + mo1, 64, w, lane);
    #pragma unroll
    for (int c = 0; c < 8; c += 4) {
      const int cc = c + w;
      const int row0 = cc << 3;
      const int row = row0 + (lane >> 3);
      const int ch = (lane & 7) ^ (row & 7);
      const int mg = ((ch >> 2) ? 512 : 0) + t * 32 + ((ch & 3) << 3);
      gl16(vbh + (size_t)row * 1024 + mg, sb + 16384 + row0 * 64);
    }
    __syncthreads();
    f32x16 aS = {}, aG = {};
    #pragma unroll
    for (int ks = 0; ks < 4; ++ks) {
      const int row = mh * 32 + lc;
      const int ck = ks * 2 + hl;
      const short8 Ah_ = frag(sb, row, ck);
      const short8 Al_ = frag(sb + 4096, row, ck);
      const short8 Eh_ = frag(sb + 8192, row, ck);
      const short8 El_ = frag(sb + 12288, row, ck);
      aS = MFMA32(Ah_, qB[ks], aS);
      aS = MFMA32(Al_, qB[ks], aS);
      aS = MFMA32(Ah_, qlB[ks], aS);
      aG = MFMA32(Eh_, gB[ks], aG);
      aG = MFMA32(El_, gB[ks], aG);
      aG = MFMA32(Eh_, glB[ks], aG);
    }
    float a[16];
    #pragma unroll
    for (int r = 0; r < 16; ++r) {
      const float g = aG[r];
      const float p = __expf(aS[r] * g) * rdn;
      a[r] = om * p + ah_ * g;
    }
    short8 pf[2];
    {
      uint W[8], Ws[8];
      #pragma unroll
      for (int j = 0; j < 8; ++j) W[j] = packbf(a[2 * j], a[2 * j + 1]);
      #pragma unroll
      for (int j = 0; j < 8; ++j) Ws[j] = __shfl_xor(W[j], 32);
      uint4v b0, b1;
      b0[0] = hl ? Ws[2] : W[0];  b0[1] = hl ? Ws[3] : W[1];
      b0[2] = hl ? W[2]  : Ws[0]; b0[3] = hl ? W[3]  : Ws[1];
      b1[0] = hl ? Ws[6] : W[4];  b1[1] = hl ? Ws[7] : W[5];
      b1[2] = hl ? W[6]  : Ws[4]; b1[3] = hl ? W[7]  : Ws[5];
      pf[0] = __builtin_bit_cast(short8, b0);
      pf[1] = __builtin_bit_cast(short8, b1);
    }
    #pragma unroll
    for (int dt = 0; dt < 2; ++dt)
      #pragma unroll
      for (int ks = 0; ks < 2; ++ks) {
        const short8 va = frag(sb + 16384, dt * 32 + lc, mh * 4 + ks * 2 + hl);
        oac[dt] = MFMA32(va, pf[ks], oac[dt]);
      }
  }
  __syncthreads();
  float* buf = (float*)sb;
  if (mh == 1) {
    #pragma unroll
    for (int dt = 0; dt < 2; ++dt)
      #pragma unroll
      for (int r = 0; r < 16; ++r) {
        const int d = dt * 32 + (r & 3) + ((r >> 2) << 3) + (hl << 2);
        buf[(nw * 32 + lc) * 68 + d] = oac[dt][r];
      }
  }
  __syncthreads();
  if (mh == 0) {
    #pragma unroll
    for (int dt = 0; dt < 2; ++dt)
      #pragma unroll
      for (int r = 0; r < 16; ++r) {
        const int d = dt * 32 + (r & 3) + ((r >> 2) << 3) + (hl << 2);
        const int idx = (nw * 32 + lc) * 68 + d;
        buf[idx] = oac[dt][r] + buf[idx];
      }
  }
  __syncthreads();
  {
    const int rowi = tid >> 2;
    const int d0 = (tid & 3) << 4;
    float f[16] __attribute__((aligned(16)));
    #pragma unroll
    for (int j = 0; j < 4; ++j)
      *(float4*)(f + 4 * j) = *(const float4*)(&buf[rowi * 68 + d0 + 4 * j]);
    const int n = n0 + rowi;
    short* dsth = ctxh + (size_t)(b * kN + n) * kDim + h * 64 + d0;
    short* dstl = ctxl + (size_t)(b * kN + n) * kDim + h * 64 + d0;
    #pragma unroll
    for (int g8 = 0; g8 < 2; ++g8) {
      short8 hi, lo;
      split8(f + 8 * g8, hi, lo);
      *(short8*)(dsth + 8 * g8) = hi;
      *(short8*)(dstl + 8 * g8) = lo;
    }
  }
}

// ---------------- K6: out = ctx @ W_proj^T + b_proj, bf16x4, 2-phase --------
__global__ __launch_bounds__(512) void k_proj(const short* __restrict__ ch_,
                                              const short* __restrict__ cl_,
                                              const short* __restrict__ wh,
                                              const short* __restrict__ wl,
                                              const float* __restrict__ bias,
                                              float* __restrict__ out) {
  __shared__ __align__(16) short sb[2][32768];
  const int bx = blockIdx.x, by = blockIdx.y;
  const int tid = threadIdx.x, w = tid >> 6, lane = tid & 63;
  const int wr = w >> 2, wc = w & 3;
  const short* Asrc_h = ch_ + (size_t)(by * 128) * kDim;
  const short* Asrc_l = cl_ + (size_t)(by * 128) * kDim;
  const short* Bsrc_h = wh + (size_t)(bx * 128) * kDim;
  const short* Bsrc_l = wl + (size_t)(bx * 128) * kDim;

  f32x4 acc[4][2] = {};
  {
    short* nb = sb[0];
    stage_tile<128, 8>(nb,         Asrc_h, kDim, w, lane);
    stage_tile<128, 8>(nb + 8192,  Asrc_l, kDim, w, lane);
    stage_tile<128, 8>(nb + 16384, Bsrc_h, kDim, w, lane);
    stage_tile<128, 8>(nb + 24576, Bsrc_l, kDim, w, lane);
  }
  int p = 0;
  #pragma unroll 1
  for (int t = 0; t < 12; ++t) {
    __syncthreads();
    if (t < 11) {
      const int k0 = (t + 1) * 64;
      short* nb = sb[p ^ 1];
      stage_tile<128, 8>(nb,         Asrc_h + k0, kDim, w, lane);
      stage_tile<128, 8>(nb + 8192,  Asrc_l + k0, kDim, w, lane);
      stage_tile<128, 8>(nb + 16384, Bsrc_h + k0, kDim, w, lane);
      stage_tile<128, 8>(nb + 24576, Bsrc_l + k0, kDim, w, lane);
    }
    const short* cb = sb[p];
    #pragma unroll
    for (int s = 0; s < 2; ++s) {
      const int ch = (s << 2) + (lane >> 4);
      short8 af[4], alf[4], bf_[2], blf[2];
      #pragma unroll
      for (int i = 0; i < 4; i++) {
        const int ar = wr * 64 + i * 16 + (lane & 15);
        af[i]  = frag(cb, ar, ch);
        alf[i] = frag(cb + 8192, ar, ch);
      }
      #pragma unroll
      for (int j = 0; j < 2; j++) {
        const int br = wc * 32 + j * 16 + (lane & 15);
        bf_[j] = frag(cb + 16384, br, ch);
        blf[j] = frag(cb + 24576, br, ch);
      }
      #pragma unroll
      for (int i = 0; i < 4; i++)
        #pragma unroll
        for (int j = 0; j < 2; j++) {
          acc[i][j] = MFMA(af[i], bf_[j], acc[i][j]);
          acc[i][j] = MFMA(af[i], blf[j], acc[i][j]);
          acc[i][j] = MFMA(alf[i], bf_[j], acc[i][j]);
          acc[i][j] = MFMA(alf[i], blf[j], acc[i][j]);
        }
    }
    p ^= 1;
  }
  #pragma unroll
  for (int j = 0; j < 2; j++) {
    const int col = bx * 128 + wc * 32 + j * 16 + (lane & 15);
    const float bv = bias[col];
    #pragma unroll
    for (int i = 0; i < 4; i++) {
      #pragma unroll
      for (int r = 0; r < 4; r++) {
        const int row = by * 128 + wr * 64 + i * 16 + ((lane >> 4) << 2) + r;
        out[(size_t)row * kDim + col] = acc[i][j][r] + bv;
      }
    }
  }
}

}  // namespace

extern "C" void kernel_launch(void* const* d_in, const int* in_sizes, int n_in,
                              void* d_out, int out_size, void* d_ws, size_t ws_size,
                              hipStream_t stream) {
  const float* x     = (const float*)d_in[0];
  const float* Wqkv  = (const float*)d_in[1];
  const float* bqkv  = (const float*)d_in[2];
  const float* Wgp   = (const float*)d_in[3];
  const float* alpha = (const float*)d_in[4];
  const float* Wproj = (const float*)d_in[5];
  const float* bproj = (const float*)d_in[6];
  float* out = (float*)d_out;

  // base workspace: 10 bf16 regions of 3,145,728 elems + 2 small fp32 (63.3MB)
  // Aliases: Wq-split in gw region; vt in vl region (vl dead after k_gw);
  //          ctx in x region; Wp-split in q region.
  // mat-path extra: A fp16 [48][1024][1024] = 96MB appended (total ~164MB).
  const size_t he = 3145728;
  short* qh  = (short*)d_ws;
  short* ql  = qh + he;
  short* kh  = ql + he;
  short* kl  = kh + he;
  short* vh  = kl + he;
  short* vl  = vh + he;
  short* gwh = vl + he;
  short* gwl = gwh + he;
  short* xh  = gwl + he;
  short* xl  = xh + he;
  float* rdenom = (float*)(xl + he);
  float* rcolv  = rdenom + (size_t)kBH * kN;
  ushort* Ab    = (ushort*)(rcolv + (size_t)kBH * kN);
  const size_t need_mat = (size_t)(rcolv + (size_t)kBH * kN - (float*)d_ws) * 4
                        + (size_t)kBH * kN * kN * 2;
  const bool mat = ws_size >= need_mat;

  short* Wqh = gwh;  short* Wql = gwl;
  short* vt  = vl;            // [48][64][1024] rcol-scaled V^T (fp16 or bf16)
  short* ctxh = xh;  short* ctxl = xl;
  short* Wph = qh;   short* Wpl = ql;

  k_split<<<3072, 256, 0, stream>>>(x, xh, xl);
  k_split<<<1728, 256, 0, stream>>>(Wqkv, Wqh, Wql);
  k_qkv  <<<dim3(18, 32), 512, 0, stream>>>(xh, xl, Wqh, Wql, bqkv,
                                            qh, ql, kh, kl, vh, vl);
  k_gw   <<<dim3(kBH, 8), 512, 0, stream>>>(vh, vl, Wgp, gwh, gwl);
  k_denom<<<dim3(kBH, 16), 256, 0, stream>>>(qh, ql, kh, kl, gwh, gwl, rdenom);
  if (mat) {
    k_colsum<1><<<dim3(kBH, 16), 256, 0, stream>>>(qh, ql, kh, kl, gwh, gwl,
                                                   rdenom, alpha, rcolv, Ab);
    k_vt<1> <<<dim3(kBH, 16), 256, 0, stream>>>(vh, rcolv, vt);
    k_outA  <<<dim3(kBH, 16), 256, 0, stream>>>(Ab, vt, ctxh, ctxl);
  } else {
    k_colsum<0><<<dim3(kBH, 16), 256, 0, stream>>>(qh, ql, kh, kl, gwh, gwl,
                                                   rdenom, alpha, rcolv, nullptr);
    k_vt<0> <<<dim3(kBH, 16), 256, 0, stream>>>(vh, rcolv, vt);
    k_out9  <<<dim3(kBH, 16), 256, 0, stream>>>(qh, ql, kh, kl, vt, gwh, gwl,
                                                rdenom, alpha, ctxh, ctxl);
  }
  k_split<<<576, 256, 0, stream>>>(Wproj, Wph, Wpl);
  k_proj <<<dim3(6, 32), 512, 0, stream>>>(ctxh, ctxl, Wph, Wpl, bproj, out);
}